// Round 13
// baseline (4301.720 us; speedup 1.0000x reference)
//
#include <hip/hip_runtime.h>
#include <hip/hip_bf16.h>
#include <cstdint>
#include <cstddef>

using f16 = _Float16;
typedef _Float16 f16x2 __attribute__((ext_vector_type(2)));
typedef _Float16 f16x8 __attribute__((ext_vector_type(8)));
typedef float f32x4 __attribute__((ext_vector_type(4)));

static constexpr int DD = 31;                      // depth (time) extent
static constexpr long long U  = 31LL * 256 * 256;  // 2,031,616 elems (1 ch @256)
static constexpr long long V2 = 31LL * 128 * 128;  //   507,904 (1 ch @128)
static constexpr long long POOL_UNITS = 56;        // pool = 56*U f16 elems (~227MB)
static constexpr int CP_CHUNK = 16;                // LDS weight chunk (ci pairs)
static constexpr int COSPLIT_NONE = 1 << 30;

union U32H2 { unsigned u; f16x2 h; };

__device__ __forceinline__ float toF(float v) { return v; }
__device__ __forceinline__ float toF(f16 v) { return (float)v; }
__device__ __forceinline__ void stv(float* p, float v) { *p = v; }
__device__ __forceinline__ void stv(f16* p, float v) { *p = (f16)v; }
__device__ __forceinline__ float sigm(float x) { return 1.f / (1.f + __expf(-x)); }

__device__ __forceinline__ unsigned packh2(float a, float b)
{
    U32H2 r; r.h = f16x2{(f16)a, (f16)b}; return r.u;
}
__device__ __forceinline__ unsigned addh2(unsigned a, unsigned b)
{
    U32H2 x, y, r; x.u = a; y.u = b; r.h = x.h + y.h; return r.u;
}
__device__ __forceinline__ float dot2f(unsigned v, unsigned w, float c)
{
#if __has_builtin(__builtin_amdgcn_fdot2)
    U32H2 uv, uw; uv.u = v; uw.u = w;
    return __builtin_amdgcn_fdot2(uv.h, uw.h, c, false);
#else
    U32H2 uv, uw; uv.u = v; uw.u = w;
    c = fmaf((float)uv.h.x, (float)uw.h.x, c);
    return fmaf((float)uv.h.y, (float)uw.h.y, c);
#endif
}

// ---------------------------------------------------------------------------
__global__ __launch_bounds__(256)
void fill_k(f16* p, long long n)
{
    const long long stride = (long long)gridDim.x * 256;
    for (long long i = (long long)blockIdx.x * 256 + threadIdx.x; i < n; i += stride)
        p[i] = (f16)0.f;
}

// a += b elementwise (f16, 8-wide). Pre-sums skip inputs so the up-conv
// stages ONE tensor (r12: FETCH 382->95MB). Bitwise-identical f16 adds.
__global__ __launch_bounds__(256)
void add_k(f16* __restrict__ a, const f16* __restrict__ b, long long n8)
{
    const long long i = (long long)blockIdx.x * 256 + threadIdx.x;
    if (i >= n8) return;
    uint4 va = ((const uint4*)a)[i];
    const uint4 vb = ((const uint4*)b)[i];
    va.x = addh2(va.x, vb.x); va.y = addh2(va.y, vb.y);
    va.z = addh2(va.z, vb.z); va.w = addh2(va.w, vb.w);
    ((uint4*)a)[i] = va;
}

// ---------------------------------------------------------------------------
// Weight prepack: fp32 [nCo][CIN][27] -> f16x8 MFMA B-fragments, FLIP folded.
// Entry e = ((cc*nhg + hg)*9 + kd*3+Tg)*64 + lane; lane l holds co hg*8+(l&15)
// tap T=Tg*4+(l>>4), elems = 8 ci of chunk cc. nhg = ceil(nCo/8).
// ---------------------------------------------------------------------------
__global__ __launch_bounds__(256)
void pack_w_k(const float* __restrict__ wt, f16* __restrict__ outp,
              int CIN, int nCo, int flip)
{
    const int e = blockIdx.x * 256 + threadIdx.x;
    const int nhg = (nCo + 7) >> 3;
    const int total = (CIN >> 3) * nhg * 9 * 64;
    if (e >= total) return;
    const int l = e & 63;
    const int r = e >> 6;
    const int r9 = r % 9;
    const int t2 = r / 9;
    const int hg = t2 % nhg;
    const int cc = t2 / nhg;
    const int kd = r9 / 3, Tg = r9 - kd * 3;
    const int n = hg * 8 + (l & 15);
    const int T = Tg * 4 + (l >> 4);
    f16x8 bv;
#pragma unroll
    for (int i = 0; i < 8; ++i) bv[i] = (f16)0.f;
    if (T <= 8 && n < nCo) {
        const int kh = T / 3, kw = T - (T / 3) * 3;
        const int st = flip ? ((2 - kd) * 9 + (2 - kh) * 3 + (2 - kw))
                            : (kd * 9 + kh * 3 + kw);
        const size_t wb8 = ((size_t)n * CIN + cc * 8) * 27 + st;
#pragma unroll
        for (int i = 0; i < 8; ++i)
            bv[i] = (f16)wt[wb8 + (size_t)i * 27];
    }
    *(f16x8*)(outp + (size_t)e * 8) = bv;
}

// ---------------------------------------------------------------------------
// MFMA implicit-GEMM conv3d, 3x3x3, pad 1, pair-interleaved in [C/2][D][H][W][2]
// f16. v_mfma_f32_16x16x32_f16. Packed-B register loads issued before the A
// barrier (r9-proven). Dual-output: rel co < coSplit -> out, else outF at
// co-coSplit (both IL). OUTIL=false -> plain [nCo][D][H][W] store (rec).
// Fragment layouts: A row=lane&15, k=(lane>>4)*8+e; B col=lane&15, same k;
// D col=lane&15, row=(lane>>4)*4+reg [m89/m91].
// ---------------------------------------------------------------------------
template<int STRIDE, bool FLIP, int CIN, int HOUT, int WOUT, int NT, bool PACKED,
         bool OUTIL>
__global__ __launch_bounds__(256)
void conv_mfma_k(const f16* __restrict__ in, const float* __restrict__ wt,
                 const f16x8* __restrict__ wb, const float* __restrict__ bias,
                 f16* __restrict__ out, f16* __restrict__ outF, int coSplit,
                 int nCo, int cg0, int nhg)
{
    constexpr int CIC = CIN / 8;
    constexpr int HIN = HOUT * STRIDE, WIN = WOUT * STRIDE;
    constexpr int WT = (WOUT > 128) ? 128 : WOUT;   // 128 or 64
    constexpr int RR = 128 / WT;                    // rows per block
    constexpr int COLS = WOUT / WT;
    constexpr int TPD = (HOUT / RR) * COLS;
    constexpr int AH = STRIDE * (RR - 1) + 3;
    constexpr int AW = STRIDE * (WT - 1) + 3;
    constexpr int APOS = 3 * AH * AW;
    constexpr int NBENT = NT * 576;                 // B entries (fallback)

    extern __shared__ unsigned lds[];
    unsigned* Alds = lds;                           // APOS*4 dwords
    unsigned* Blds = lds + APOS * 4;                // fallback only

    const int tid = threadIdx.x;
    const int l = tid & 63;
    const int wid = tid >> 6;

    const int bx = blockIdx.x;
    const int d0 = bx / TPD;
    const int rem = bx - d0 * TPD;
    const int h0 = (rem / COLS) * RR;
    const int wb_ = (rem % COLS) * WT;

    const int co_base = blockIdx.y * (16 * NT);
    const int nRem = nCo - co_base;
    const int hgBase = cg0 + blockIdx.y * (2 * NT);

    const int base_h = STRIDE * h0 - 1;
    const int base_w = STRIDE * wb_ - 1;
    constexpr size_t HWin = (size_t)HIN * WIN;
    constexpr size_t DHW = (size_t)DD * HWin;       // dwords per channel-pair
    const unsigned* inu = (const unsigned*)in;

    // spatial decode for this lane's two A m-tiles
    int hho[2], wlo[2];
#pragma unroll
    for (int mt = 0; mt < 2; ++mt) {
        const int p = wid * 32 + mt * 16 + (l & 15);
        hho[mt] = p / WT;
        wlo[mt] = p - hho[mt] * WT;
    }
    // lane's tap slot per tap-group
    const int g = l >> 4;
    int khg[3], kwg[3];
#pragma unroll
    for (int Tg = 0; Tg < 3; ++Tg) {
        int T = Tg * 4 + g;
        if (T > 8) T = 8;                           // clamped; B is zero there
        khg[Tg] = T / 3;
        kwg[Tg] = T - (T / 3) * 3;
    }

    f32x4 acc[2][NT];
#pragma unroll
    for (int mt = 0; mt < 2; ++mt)
#pragma unroll
        for (int nt = 0; nt < NT; ++nt)
            acc[mt][nt] = (f32x4){0.f, 0.f, 0.f, 0.f};

    for (int cc = 0; cc < CIC; ++cc) {
        // ---- PACKED: issue B register loads early (latency hides under A) -
        f16x8 bfr[NT][9];
        if (PACKED) {
#pragma unroll
            for (int nt = 0; nt < NT; ++nt)
#pragma unroll
                for (int r9 = 0; r9 < 9; ++r9)
                    bfr[nt][r9] = wb[((size_t)cc * nhg + hgBase + nt * 2) * 9 * 64
                                     + (size_t)r9 * 64 + l];
        }
        __syncthreads();
        // ---- stage A chunk: 4 cp (8 ci) per position ----------------------
        for (int t = tid; t < APOS; t += 256) {
            const int ww = t % AW;
            const int t2 = t / AW;
            const int hh = t2 % AH;
            const int dd = t2 / AH;
            const int d = d0 - 1 + dd;
            const int h = base_h + hh;
            const int w = base_w + ww;
            uint4 val = make_uint4(0u, 0u, 0u, 0u);
            if ((unsigned)d < (unsigned)DD && (unsigned)h < (unsigned)HIN &&
                (unsigned)w < (unsigned)WIN) {
                const size_t gi = (size_t)(cc * 4) * DHW +
                                  (size_t)d * HWin + (size_t)h * WIN + w;
                val.x = inu[gi];
                val.y = inu[gi + DHW];
                val.z = inu[gi + 2 * DHW];
                val.w = inu[gi + 3 * DHW];
            }
            *(uint4*)(Alds + (size_t)t * 4) = val;
        }
        // ---- fallback: stage B fragments via fp32 gather ------------------
        if (!PACKED) {
            for (int t = tid; t < NBENT; t += 256) {
                const int ll = t & 63;
                const int f = t >> 6;
                const int nt = f / 9;
                const int r9 = f - nt * 9;
                const int kd = r9 / 3;
                const int Tg = r9 - kd * 3;
                const int n = nt * 16 + (ll & 15);
                const int gg = ll >> 4;
                const int T = Tg * 4 + gg;
                f16x8 bv;
                if (T <= 8 && n < nRem) {
                    const int kh = T / 3, kw = T - (T / 3) * 3;
                    const int st = FLIP ? ((2 - kd) * 9 + (2 - kh) * 3 + (2 - kw))
                                        : (kd * 9 + kh * 3 + kw);
                    const size_t wb8 = ((size_t)(co_base + n) * CIN + cc * 8) * 27 + st;
#pragma unroll
                    for (int e = 0; e < 8; ++e)
                        bv[e] = (f16)wt[wb8 + (size_t)e * 27];
                } else {
#pragma unroll
                    for (int e = 0; e < 8; ++e) bv[e] = (f16)0.f;
                }
                *(f16x8*)(Blds + (size_t)t * 4) = bv;
            }
        }
        __syncthreads();
        // ---- compute: 3 kd x 3 tap-groups x 2 m-tiles x NT n-tiles --------
#pragma unroll
        for (int kd = 0; kd < 3; ++kd) {
#pragma unroll
            for (int Tg = 0; Tg < 3; ++Tg) {
                f16x8 bfrag[NT];
#pragma unroll
                for (int nt = 0; nt < NT; ++nt)
                    bfrag[nt] = PACKED ? bfr[nt][kd * 3 + Tg]
                                       : *(const f16x8*)
                        (Blds + (size_t)(((nt * 9) + kd * 3 + Tg) * 64 + l) * 4);
                const int kh = khg[Tg], kw = kwg[Tg];
#pragma unroll
                for (int mt = 0; mt < 2; ++mt) {
                    const int hh = STRIDE * hho[mt] + kh;
                    const int ww = STRIDE * wlo[mt] + kw;
                    const f16x8 afrag = *(const f16x8*)
                        (Alds + (size_t)((kd * AH + hh) * AW + ww) * 4);
#pragma unroll
                    for (int nt = 0; nt < NT; ++nt)
                        acc[mt][nt] = __builtin_amdgcn_mfma_f32_16x16x32_f16(
                            afrag, bfrag[nt], acc[mt][nt], 0, 0, 0);
                }
            }
        }
    }

    // ---- store: D lane mapping col(n)=lane&15, row m=(lane>>4)*4+r --------
    const int n = l & 15;
#pragma unroll
    for (int nt = 0; nt < NT; ++nt) {
        const int ng = nt * 16 + n;
        if (ng < nRem) {
            const int co = co_base + ng;
            const float bv = bias[co];
            f16* dst = out;
            int cs = co;
            if (OUTIL && co >= coSplit) { dst = outF; cs = co - coSplit; }
#pragma unroll
            for (int mt = 0; mt < 2; ++mt) {
#pragma unroll
                for (int r = 0; r < 4; ++r) {
                    const int p = wid * 32 + mt * 16 + (l >> 4) * 4 + r;
                    const int hh = p / WT;
                    const int wl = p - hh * WT;
                    const int h = h0 + hh, w = wb_ + wl;
                    const float val = acc[mt][nt][r] + bv;
                    if (OUTIL) {
                        const size_t coPlane =
                            (size_t)(cs >> 1) * DD * HOUT * WOUT * 2 + (cs & 1);
                        dst[coPlane + ((size_t)d0 * HOUT + h) * WOUT * 2 +
                            (size_t)w * 2] = (f16)val;
                    } else {
                        out[((size_t)co * DD + d0) * HOUT * WOUT +
                            (size_t)h * WOUT + w] = (f16)val;
                    }
                }
            }
        }
    }
}

// ---------------------------------------------------------------------------
// MFMA fused conv3d( upsample2x(S) ), stride 1, no flip, IL; S pre-summed.
// r13 staging: halo stored at HI-RES granularity -- entry ww' holds
// lo[(wb-1+ww')>>1] (duplication at staging). Compute reads iw = wpos+kw:
// consecutive DISTINCT lines, the exact pattern the plain conv kernel runs
// with 0 bank conflicts. (r12 evidence: +1 row pad left 5.0e7 conflict
// cycles -- conflicts were from the pair-collapsed >>1 read, not rows.)
// Values bitwise identical to the r11/r12 mapping. RR=1. Dual-output.
// ---------------------------------------------------------------------------
template<int CIN, int HLO, int WLO, int NT>
__global__ __launch_bounds__(256)
void conv_mfma_up_k(const f16* __restrict__ in, const f16x8* __restrict__ wb,
                    const float* __restrict__ bias, f16* __restrict__ out,
                    f16* __restrict__ outF, int coSplit,
                    int nCo, int cg0, int nhg)
{
    constexpr int CIC = CIN / 8;
    constexpr int HOUT = 2 * HLO, WOUT = 2 * WLO;
    constexpr int WT = (WOUT > 128) ? 128 : WOUT;
    constexpr int COLS = WOUT / WT;
    constexpr int TPD = HOUT * COLS;                // RR = 1
    constexpr int AWHI = WT + 2;                    // hi-res halo width
    constexpr int APOS = 3 * 2 * AWHI;

    extern __shared__ unsigned lds[];               // APOS uint4

    const int tid = threadIdx.x;
    const int l = tid & 63;
    const int wid = tid >> 6;

    const int bx = blockIdx.x;
    const int d0 = bx / TPD;
    const int rem = bx - d0 * TPD;
    const int h0 = rem / COLS;
    const int wb_ = (rem % COLS) * WT;

    const int co_base = blockIdx.y * (16 * NT);
    const int nRem = nCo - co_base;
    const int hgBase = cg0 + blockIdx.y * (2 * NT);

    const int rlo0 = (h0 - 1) >> 1;                 // arithmetic shift

    constexpr size_t HWlo = (size_t)HLO * WLO;
    constexpr size_t DHW = (size_t)DD * HWlo;
    const unsigned* inu = (const unsigned*)in;

    int wpos[2];
#pragma unroll
    for (int mt = 0; mt < 2; ++mt)
        wpos[mt] = wid * 32 + mt * 16 + (l & 15);

    const int g = l >> 4;
    int khg[3], kwg[3];
#pragma unroll
    for (int Tg = 0; Tg < 3; ++Tg) {
        int T = Tg * 4 + g;
        if (T > 8) T = 8;
        khg[Tg] = T / 3;
        kwg[Tg] = T - (T / 3) * 3;
    }

    f32x4 acc[2][NT];
#pragma unroll
    for (int mt = 0; mt < 2; ++mt)
#pragma unroll
        for (int nt = 0; nt < NT; ++nt)
            acc[mt][nt] = (f32x4){0.f, 0.f, 0.f, 0.f};

    for (int cc = 0; cc < CIC; ++cc) {
        f16x8 bfr[NT][9];
#pragma unroll
        for (int nt = 0; nt < NT; ++nt)
#pragma unroll
            for (int r9 = 0; r9 < 9; ++r9)
                bfr[nt][r9] = wb[((size_t)cc * nhg + hgBase + nt * 2) * 9 * 64
                                 + (size_t)r9 * 64 + l];
        __syncthreads();
        for (int t = tid; t < APOS; t += 256) {
            const int ww = t % AWHI;                // hi-res halo col index
            const int t2 = t / AWHI;
            const int rr = t2 & 1;
            const int dd = t2 >> 1;
            const int d = d0 - 1 + dd;
            const int hlo = rlo0 + rr;
            const int wlo = (wb_ - 1 + ww) >> 1;    // arithmetic shift
            uint4 val = make_uint4(0u, 0u, 0u, 0u);
            if ((unsigned)d < (unsigned)DD && (unsigned)hlo < (unsigned)HLO &&
                (unsigned)wlo < (unsigned)WLO) {
                const size_t gi = (size_t)(cc * 4) * DHW +
                                  (size_t)d * HWlo + (size_t)hlo * WLO + wlo;
                val.x = inu[gi];
                val.y = inu[gi + DHW];
                val.z = inu[gi + 2 * DHW];
                val.w = inu[gi + 3 * DHW];
            }
            *(uint4*)(lds + (size_t)((dd * 2 + rr) * AWHI + ww) * 4) = val;
        }
        __syncthreads();
#pragma unroll
        for (int kd = 0; kd < 3; ++kd) {
#pragma unroll
            for (int Tg = 0; Tg < 3; ++Tg) {
                const int kh = khg[Tg], kw = kwg[Tg];
                const int rr = ((h0 + kh - 1) >> 1) - rlo0;   // 0 or 1
#pragma unroll
                for (int mt = 0; mt < 2; ++mt) {
                    const int iw = wpos[mt] + kw;   // consecutive distinct
                    const f16x8 afrag = *(const f16x8*)
                        (lds + (size_t)((kd * 2 + rr) * AWHI + iw) * 4);
#pragma unroll
                    for (int nt = 0; nt < NT; ++nt)
                        acc[mt][nt] = __builtin_amdgcn_mfma_f32_16x16x32_f16(
                            afrag, bfr[nt][kd * 3 + Tg], acc[mt][nt], 0, 0, 0);
                }
            }
        }
    }

    const int n = l & 15;
#pragma unroll
    for (int nt = 0; nt < NT; ++nt) {
        const int ng = nt * 16 + n;
        if (ng < nRem) {
            const int co = co_base + ng;
            const float bv = bias[co];
            f16* dst = out;
            int cs = co;
            if (co >= coSplit) { dst = outF; cs = co - coSplit; }
            const size_t coPlane = (size_t)(cs >> 1) * DD * HOUT * WOUT * 2 + (cs & 1);
#pragma unroll
            for (int mt = 0; mt < 2; ++mt) {
#pragma unroll
                for (int r = 0; r < 4; ++r) {
                    const int p = wid * 32 + mt * 16 + (l >> 4) * 4 + r;
                    dst[coPlane + ((size_t)d0 * HOUT + h0) * WOUT * 2 +
                        (size_t)(wb_ + p) * 2] = (f16)(acc[mt][nt][r] + bv);
                }
            }
        }
    }
}

// ---------------------------------------------------------------------------
// Scalar pair-interleaved direct conv3d (fallback only). W-tile 8, dot2.
// ---------------------------------------------------------------------------
template<int STRIDE, bool FLIP, int CO_BLK, bool OUT_IL>
__global__ __launch_bounds__(256, 2)
void conv3d_il_k(const f16* __restrict__ in, const float* __restrict__ wt,
                 const float* __restrict__ bias, f16* __restrict__ out,
                 int Cin, int Hin, int Win, int Hout, int Wout)
{
    extern __shared__ unsigned wl2[];  // [CP_CHUNK*27][CO_BLK]
    const int co_base = blockIdx.y * CO_BLK;

    const int s8 = (blockIdx.x * 256 + threadIdx.x) * 8;
    const int w0 = s8 % Wout;
    const int sh = s8 / Wout;
    const int h0 = sh % Hout;
    const int d0 = sh / Hout;

    float acc[CO_BLK][8];
#pragma unroll
    for (int j = 0; j < CO_BLK; ++j) {
        const float bv = bias[co_base + j];
#pragma unroll
        for (int o = 0; o < 8; ++o) acc[j][o] = bv;
    }

    const size_t HWin = (size_t)Hin * Win;
    const int CP = Cin >> 1;

    for (int cp0 = 0; cp0 < CP; cp0 += CP_CHUNK) {
        const int cnp = (CP - cp0 < CP_CHUNK) ? (CP - cp0) : CP_CHUNK;
        __syncthreads();
        for (int t = threadIdx.x; t < cnp * 27 * CO_BLK; t += 256) {
            const int j = t % CO_BLK;
            const int k = (t / CO_BLK) % 27;
            const int cp = t / (CO_BLK * 27);
            int src;
            if (FLIP) {
                const int kd = k / 9, kh = (k / 3) % 3, kw = k % 3;
                src = (2 - kd) * 9 + (2 - kh) * 3 + (2 - kw);
            } else {
                src = k;
            }
            const int ci = (cp0 + cp) * 2;
            const size_t wb = (size_t)(co_base + j) * Cin;
            wl2[t] = packh2(wt[(wb + ci) * 27 + src], wt[(wb + ci + 1) * 27 + src]);
        }
        __syncthreads();

        for (int cp = 0; cp < cnp; ++cp) {
            const f16* cb = in + (size_t)(cp0 + cp) * DD * HWin * 2;
            const unsigned* wc = wl2 + cp * 27 * CO_BLK;
#pragma unroll
            for (int kd = 0; kd < 3; ++kd) {
                const int di = d0 + kd - 1;
                if (di < 0 || di >= DD) continue;
#pragma unroll
                for (int kh = 0; kh < 3; ++kh) {
                    const int hi = h0 * STRIDE + kh - 1;
                    if (hi < 0 || hi >= Hin) continue;
                    const unsigned* rowu = (const unsigned*)
                        (cb + ((size_t)di * HWin + (size_t)hi * Win) * 2);
                    if (STRIDE == 1) {
                        unsigned v2[10];
                        v2[0] = (w0 > 0) ? rowu[w0 - 1] : 0u;
                        const uint4 q1 = *(const uint4*)(rowu + w0);
                        const uint4 q2 = *(const uint4*)(rowu + w0 + 4);
                        v2[1] = q1.x; v2[2] = q1.y; v2[3] = q1.z; v2[4] = q1.w;
                        v2[5] = q2.x; v2[6] = q2.y; v2[7] = q2.z; v2[8] = q2.w;
                        v2[9] = (w0 + 8 < Win) ? rowu[w0 + 8] : 0u;
                        const unsigned* wk = wc + (kd * 9 + kh * 3) * CO_BLK;
#pragma unroll
                        for (int kw = 0; kw < 3; ++kw) {
#pragma unroll
                            for (int j = 0; j < CO_BLK; ++j) {
                                const unsigned wv = wk[kw * CO_BLK + j];
#pragma unroll
                                for (int o = 0; o < 8; ++o)
                                    acc[j][o] = dot2f(v2[o + kw], wv, acc[j][o]);
                            }
                        }
                    } else {
                        unsigned v2[17];
                        const int p0 = w0 * 2;
                        v2[0] = (w0 > 0) ? rowu[p0 - 1] : 0u;
#pragma unroll
                        for (int q = 0; q < 4; ++q) {
                            const uint4 qq = *(const uint4*)(rowu + p0 + 4 * q);
                            v2[1 + 4 * q] = qq.x; v2[2 + 4 * q] = qq.y;
                            v2[3 + 4 * q] = qq.z; v2[4 + 4 * q] = qq.w;
                        }
                        const unsigned* wk = wc + (kd * 9 + kh * 3) * CO_BLK;
#pragma unroll
                        for (int kw = 0; kw < 3; ++kw) {
#pragma unroll
                            for (int j = 0; j < CO_BLK; ++j) {
                                const unsigned wv = wk[kw * CO_BLK + j];
#pragma unroll
                                for (int o = 0; o < 8; ++o)
                                    acc[j][o] = dot2f(v2[2 * o + kw], wv, acc[j][o]);
                            }
                        }
                    }
                }
            }
        }
    }

    if (OUT_IL) {
#pragma unroll
        for (int pj = 0; pj < CO_BLK / 2; ++pj) {
            f16* op = out + ((((size_t)((co_base >> 1) + pj) * DD + d0) * Hout + h0)
                             * Wout + w0) * 2;
            unsigned dw[8];
#pragma unroll
            for (int o = 0; o < 8; ++o)
                dw[o] = packh2(acc[2 * pj][o], acc[2 * pj + 1][o]);
            *(uint4*)op = make_uint4(dw[0], dw[1], dw[2], dw[3]);
            *(uint4*)(op + 8) = make_uint4(dw[4], dw[5], dw[6], dw[7]);
        }
    } else {
#pragma unroll
        for (int j = 0; j < CO_BLK; ++j) {
            f16* op = out + (((size_t)(co_base + j) * DD + d0) * Hout + h0) * Wout + w0;
            unsigned dw[4];
#pragma unroll
            for (int o = 0; o < 4; ++o)
                dw[o] = packh2(acc[j][2 * o], acc[j][2 * o + 1]);
            *(uint4*)op = make_uint4(dw[0], dw[1], dw[2], dw[3]);
        }
    }
}

// ---------------------------------------------------------------------------
// Scalar fused conv3d( upsample2x(a + b) ) (fallback only).
// ---------------------------------------------------------------------------
template<int CO_BLK>
__global__ __launch_bounds__(256, 2)
void conv3d_up_il_k(const f16* __restrict__ ia, const f16* __restrict__ ib,
                    const float* __restrict__ wt, const float* __restrict__ bias,
                    f16* __restrict__ out, int Cin, int Hlo, int Wlo)
{
    extern __shared__ unsigned wl2[];
    const int co_base = blockIdx.y * CO_BLK;

    const int Hout = 2 * Hlo, Wout = 2 * Wlo;
    const int s8 = (blockIdx.x * 256 + threadIdx.x) * 8;
    const int w0 = s8 % Wout;
    const int sh = s8 / Wout;
    const int h0 = sh % Hout;
    const int d0 = sh / Hout;
    const int lw = w0 >> 1;  // multiple of 4

    float acc[CO_BLK][8];
#pragma unroll
    for (int j = 0; j < CO_BLK; ++j) {
        const float bv = bias[co_base + j];
#pragma unroll
        for (int o = 0; o < 8; ++o) acc[j][o] = bv;
    }
    const size_t HWlo = (size_t)Hlo * Wlo;
    const int CP = Cin >> 1;

    for (int cp0 = 0; cp0 < CP; cp0 += CP_CHUNK) {
        const int cnp = (CP - cp0 < CP_CHUNK) ? (CP - cp0) : CP_CHUNK;
        __syncthreads();
        for (int t = threadIdx.x; t < cnp * 27 * CO_BLK; t += 256) {
            const int j = t % CO_BLK;
            const int k = (t / CO_BLK) % 27;
            const int cp = t / (CO_BLK * 27);
            const int ci = (cp0 + cp) * 2;
            const size_t wb = (size_t)(co_base + j) * Cin;
            wl2[t] = packh2(wt[(wb + ci) * 27 + k], wt[(wb + ci + 1) * 27 + k]);
        }
        __syncthreads();

        for (int cp = 0; cp < cnp; ++cp) {
            const f16* cba = ia + (size_t)(cp0 + cp) * DD * HWlo * 2;
            const f16* cbb = ib + (size_t)(cp0 + cp) * DD * HWlo * 2;
            const unsigned* wc = wl2 + cp * 27 * CO_BLK;
#pragma unroll
            for (int kd = 0; kd < 3; ++kd) {
                const int di = d0 + kd - 1;
                if (di < 0 || di >= DD) continue;
#pragma unroll
                for (int kh = 0; kh < 3; ++kh) {
                    const int hi = h0 + kh - 1;
                    if (hi < 0 || hi >= Hout) continue;
                    const int hlo = hi >> 1;
                    const unsigned* rua = (const unsigned*)
                        (cba + ((size_t)di * HWlo + (size_t)hlo * Wlo) * 2);
                    const unsigned* rub = (const unsigned*)
                        (cbb + ((size_t)di * HWlo + (size_t)hlo * Wlo) * 2);
                    unsigned u[6];
                    u[0] = (lw > 0) ? addh2(rua[lw - 1], rub[lw - 1]) : 0u;
                    const uint4 qa = *(const uint4*)(rua + lw);
                    const uint4 qb = *(const uint4*)(rub + lw);
                    u[1] = addh2(qa.x, qb.x); u[2] = addh2(qa.y, qb.y);
                    u[3] = addh2(qa.z, qb.z); u[4] = addh2(qa.w, qb.w);
                    u[5] = (lw + 4 < Wlo) ? addh2(rua[lw + 4], rub[lw + 4]) : 0u;
                    // upsampled window: up-w = w0-1+t, t in [0,10)
                    const unsigned v2[10] = { u[0], u[1], u[1], u[2], u[2],
                                              u[3], u[3], u[4], u[4], u[5] };
                    const unsigned* wk = wc + (kd * 9 + kh * 3) * CO_BLK;
#pragma unroll
                    for (int kw = 0; kw < 3; ++kw) {
#pragma unroll
                        for (int j = 0; j < CO_BLK; ++j) {
                            const unsigned wv = wk[kw * CO_BLK + j];
#pragma unroll
                            for (int o = 0; o < 8; ++o)
                                acc[j][o] = dot2f(v2[o + kw], wv, acc[j][o]);
                        }
                    }
                }
            }
        }
    }
#pragma unroll
    for (int pj = 0; pj < CO_BLK / 2; ++pj) {
        f16* op = out + ((((size_t)((co_base >> 1) + pj) * DD + d0) * Hout + h0)
                         * Wout + w0) * 2;
        unsigned dw[8];
#pragma unroll
        for (int o = 0; o < 8; ++o)
            dw[o] = packh2(acc[2 * pj][o], acc[2 * pj + 1][o]);
        *(uint4*)op = make_uint4(dw[0], dw[1], dw[2], dw[3]);
        *(uint4*)(op + 8) = make_uint4(dw[4], dw[5], dw[6], dw[7]);
    }
}

// ---------------------------------------------------------------------------
// fe conv: Cin=1, fp32 plain input x, interleaved f16 out (CO_BLK=4). @256^2.
// ---------------------------------------------------------------------------
__global__ __launch_bounds__(256, 2)
void conv_fe_k(const float* __restrict__ in, const float* __restrict__ wt,
               const float* __restrict__ bias, f16* __restrict__ out)
{
    __shared__ float wl[27 * 4];
    for (int t = threadIdx.x; t < 27 * 4; t += 256) {
        const int j = t % 4;
        const int k = t / 4;
        wl[t] = wt[(size_t)j * 27 + k];
    }
    __syncthreads();

    const int W = 256, H = 256;
    const int s8 = (blockIdx.x * 256 + threadIdx.x) * 8;
    const int w0 = s8 % W;
    const int sh = s8 / W;
    const int h0 = sh % H;
    const int d0 = sh / H;

    float acc[4][8];
#pragma unroll
    for (int j = 0; j < 4; ++j) {
        const float bv = bias[j];
#pragma unroll
        for (int o = 0; o < 8; ++o) acc[j][o] = bv;
    }
    const size_t HW = 65536;

#pragma unroll
    for (int kd = 0; kd < 3; ++kd) {
        const int di = d0 + kd - 1;
        if (di < 0 || di >= DD) continue;
#pragma unroll
        for (int kh = 0; kh < 3; ++kh) {
            const int hi = h0 + kh - 1;
            if (hi < 0 || hi >= H) continue;
            const float* row = in + (size_t)di * HW + (size_t)hi * W + w0;
            float v[10];
            v[0] = (w0 > 0) ? row[-1] : 0.f;
            const float4 q1 = *(const float4*)row;
            const float4 q2 = *(const float4*)(row + 4);
            v[1] = q1.x; v[2] = q1.y; v[3] = q1.z; v[4] = q1.w;
            v[5] = q2.x; v[6] = q2.y; v[7] = q2.z; v[8] = q2.w;
            v[9] = (w0 + 8 < W) ? row[8] : 0.f;
            const float* wk = wl + (kd * 9 + kh * 3) * 4;
#pragma unroll
            for (int kw = 0; kw < 3; ++kw) {
#pragma unroll
                for (int j = 0; j < 4; ++j) {
                    const float wv = wk[kw * 4 + j];
#pragma unroll
                    for (int o = 0; o < 8; ++o)
                        acc[j][o] = fmaf(v[o + kw], wv, acc[j][o]);
                }
            }
        }
    }
#pragma unroll
    for (int pj = 0; pj < 2; ++pj) {
        f16* op = out + (((size_t)pj * DD + d0) * H + h0) * (size_t)W * 2 + (size_t)w0 * 2;
        unsigned dw[8];
#pragma unroll
        for (int o = 0; o < 8; ++o)
            dw[o] = packh2(acc[2 * pj][o], acc[2 * pj + 1][o]);
        *(uint4*)op = make_uint4(dw[0], dw[1], dw[2], dw[3]);
        *(uint4*)(op + 8) = make_uint4(dw[4], dw[5], dw[6], dw[7]);
    }
}

// ---------------------------------------------------------------------------
// fo_pool over D=31. IL=true: pair-interleaved [C/2][D][HW][2]; else plain
// [C][D][HW]. out = h_d + a1? + a2?  In-place (out==z) is safe.
// ---------------------------------------------------------------------------
template<bool IL, typename TA1, typename TA2, typename TO>
__global__ __launch_bounds__(256)
void fo_pool_k(const f16* __restrict__ z, const f16* __restrict__ f,
               TO* __restrict__ out, const TA1* __restrict__ a1,
               const TA2* __restrict__ a2, int C, int HW, int reverse)
{
    const long long idx = (long long)blockIdx.x * 256 + threadIdx.x;
    if (idx >= (long long)C * HW) return;
    size_t base; size_t step;
    if (IL) {
        const long long pairIdx = idx / (2LL * HW);
        const int rem = (int)(idx - pairIdx * 2LL * HW);
        const int p = rem >> 1;
        const int par = rem & 1;
        base = ((size_t)pairIdx * DD * HW + p) * 2 + par;
        step = (size_t)HW * 2;
    } else {
        const int c = (int)(idx / HW);
        const int p = (int)(idx - (long long)c * HW);
        base = (size_t)c * DD * HW + p;
        step = (size_t)HW;
    }
    float h = 0.f;
    if (!reverse) {
        for (int d = 0; d < DD; ++d) {
            const size_t off = base + (size_t)d * step;
            const float zz = tanhf(toF(z[off]));
            const float ff = sigm(toF(f[off]));
            h = ff * h + (1.f - ff) * zz;
            float v = h;
            if (a1) v += toF(a1[off]);
            if (a2) v += toF(a2[off]);
            stv(out + off, v);
        }
    } else {
        for (int d = DD - 1; d >= 0; --d) {
            const size_t off = base + (size_t)d * step;
            const float zz = tanhf(toF(z[off]));
            const float ff = sigm(toF(f[off]));
            h = ff * h + (1.f - ff) * zz;
            float v = h;
            if (a1) v += toF(a1[off]);
            if (a2) v += toF(a2[off]);
            stv(out + off, v);
        }
    }
}

// Diagnostic: encode ws_size (MB) into output if workspace too small.
__global__ __launch_bounds__(256)
void diag_k(float* out, float v, int n)
{
    const int i = blockIdx.x * 256 + threadIdx.x;
    if (i < n) out[i] = v;
}

// ---------------------------------------------------------------------------

template<int STRIDE, bool FLIP, int CIN, int HOUT, int WOUT, int NT, bool PACKED,
         bool OUTIL>
static inline void mfma_launch(const f16* in, const float* w, const f16x8* wb,
                               const float* b, f16* out, f16* outF, int coSplit,
                               int co0, int nCo, int nhg, hipStream_t s)
{
    constexpr int WT = WOUT > 128 ? 128 : WOUT;
    constexpr int RR = 128 / WT;
    constexpr int AH = STRIDE * (RR - 1) + 3;
    constexpr int AW = STRIDE * (WT - 1) + 3;
    constexpr size_t lds = (size_t)(3 * AH * AW) * 16 +
                           (PACKED ? 0 : (size_t)NT * 9216);
    dim3 grid((unsigned)(DD * (HOUT / RR) * (WOUT / WT)),
              (unsigned)((nCo + 16 * NT - 1) / (16 * NT)));
    conv_mfma_k<STRIDE, FLIP, CIN, HOUT, WOUT, NT, PACKED, OUTIL>
        <<<grid, 256, lds, s>>>(
        in, w + (size_t)co0 * CIN * 27, wb, b + co0, out, outF, coSplit,
        nCo, co0 / 8, nhg);
}

template<int CIN, int HLO, int WLO, int NT>
static inline void mfma_up_launch(const f16* in, const f16x8* wb,
                                  const float* b, f16* out, f16* outF,
                                  int coSplit, int co0, int nCo,
                                  int nhg, hipStream_t s)
{
    constexpr int WOUT = 2 * WLO;
    constexpr int WT = WOUT > 128 ? 128 : WOUT;
    constexpr int AWHI = WT + 2;
    constexpr size_t lds = (size_t)(3 * 2 * AWHI) * 16;
    dim3 grid((unsigned)(DD * (2 * HLO) * (WOUT / WT)),
              (unsigned)((nCo + 16 * NT - 1) / (16 * NT)));
    conv_mfma_up_k<CIN, HLO, WLO, NT><<<grid, 256, lds, s>>>(
        in, wb, b + co0, out, outF, coSplit, nCo, co0 / 8, nhg);
}

static inline void conv_launch(const f16* in, const float* w, const float* b,
                               f16* out, int Cin, int co0, int nCo,
                               int Hin, int Win, int Hout, int Wout,
                               int stride, bool flip, hipStream_t s)
{
    const unsigned gx = (unsigned)((DD * (long long)Hout * Wout) / 2048);
    const float* wp = w + (size_t)co0 * Cin * 27;
    const float* bp = b + co0;
    const int cpc = (Cin / 2 < CP_CHUNK) ? Cin / 2 : CP_CHUNK;
    if (flip) {
        if (nCo % 4 == 0) {
            dim3 grid(gx, nCo / 4);
            conv3d_il_k<1, true, 4, true><<<grid, 256, (size_t)cpc * 27 * 4 * 4, s>>>(
                in, wp, bp, out, Cin, Hin, Win, Hout, Wout);
        } else {  // rec layer: nCo == 3, plain output
            dim3 grid(gx, 1);
            conv3d_il_k<1, true, 3, false><<<grid, 256, (size_t)cpc * 27 * 3 * 4, s>>>(
                in, wp, bp, out, Cin, Hin, Win, Hout, Wout);
        }
    } else {
        dim3 grid(gx, nCo / 8);
        conv3d_il_k<1, false, 8, true><<<grid, 256, (size_t)cpc * 27 * 8 * 4, s>>>(
            in, wp, bp, out, Cin, Hin, Win, Hout, Wout);
    }
}

static inline void conv_up_launch(const f16* ia, const f16* ib, const float* w,
                                  const float* b, f16* out, int Cin, int co0,
                                  int nCo, int Hlo, int Wlo, hipStream_t s)
{
    const unsigned gx = (unsigned)((DD * 4LL * Hlo * Wlo) / 2048);
    const int cpc = (Cin / 2 < CP_CHUNK) ? Cin / 2 : CP_CHUNK;
    if (nCo % 8 == 0) {
        dim3 grid(gx, nCo / 8);
        conv3d_up_il_k<8><<<grid, 256, (size_t)cpc * 27 * 8 * 4, s>>>(
            ia, ib, w + (size_t)co0 * Cin * 27, b + co0, out, Cin, Hlo, Wlo);
    } else {
        dim3 grid(gx, nCo / 4);
        conv3d_up_il_k<4><<<grid, 256, (size_t)cpc * 27 * 4 * 4, s>>>(
            ia, ib, w + (size_t)co0 * Cin * 27, b + co0, out, Cin, Hlo, Wlo);
    }
}

template<bool IL, typename TA1, typename TA2, typename TO>
static inline void pool_launch(const f16* z, const f16* f, TO* o, const TA1* a1,
                               const TA2* a2, int C, int HW, int rev,
                               hipStream_t s)
{
    const long long tot = (long long)C * HW;
    fo_pool_k<IL, TA1, TA2, TO><<<(unsigned)((tot + 255) / 256), 256, 0, s>>>(
        z, f, o, a1, a2, C, HW, rev);
}

static inline void pack_launch(const float* w, f16* outp, int CIN, int nCo,
                               int flip, hipStream_t s)
{
    const int total = (CIN / 8) * ((nCo + 7) / 8) * 9 * 64;
    pack_w_k<<<(total + 255) / 256, 256, 0, s>>>(w, outp, CIN, nCo, flip);
}

static inline void add_launch(f16* a, const f16* b, long long n, hipStream_t s)
{
    const long long n8 = n / 8;
    add_k<<<(unsigned)((n8 + 255) / 256), 256, 0, s>>>(a, b, n8);
}

// pack sizes in f16 elems (ceil co groups)
static constexpr size_t pk_sz(int CIN, int nCo)
{ return (size_t)(CIN / 8) * ((nCo + 7) / 8) * 9 * 64 * 8; }

// ---------------------------------------------------------------------------
// Memory plan (units of U). Pool = 56 U f16; packed weights (<1U) at 56U.
// r13: d1 passes 4 -> 2 (NT=2): z (co 0-31, 32ch@128^2 = 8U) directly into
// D1 region [36U,44U) + in-place pool; f (co 32-63) -> G [48U,56U) = 8U.
// All write extents audited against slots (r10 lesson).
// ---------------------------------------------------------------------------
static void run_net(const float* x, const float* const* W, const float* const* B,
                    float* out, f16* P, bool packed, hipStream_t s)
{
    const f16* np = nullptr;
    const float* npf = nullptr;

    // ---- packed-weight buffers at P + 56U ----------------------------------
    f16* WP = P + 56 * U;
    f16* PK_e0 = WP;                                  // 16,32
    f16* PK_e1 = PK_e0 + pk_sz(16, 32);               // 16,64
    f16* PK_e2 = PK_e1 + pk_sz(16, 64);               // 32,64
    f16* PK_e3 = PK_e2 + pk_sz(32, 64);               // 32,128
    f16* PK_e4 = PK_e3 + pk_sz(32, 128);              // 64,128
    f16* PK_d0 = PK_e4 + pk_sz(64, 128);              // 64,128 flip
    f16* PK_d2 = PK_d0 + pk_sz(64, 128);              // 32,64 flip
    // late packs reuse PK_d0's region (dead after d0 conv):
    f16* PK_d1 = PK_d0;                               // 64,64
    f16* PK_d3 = PK_d1 + pk_sz(64, 64);               // 32,32
    f16* PK_d4 = PK_d3 + pk_sz(32, 32);               // 16,32 flip
    f16* PK_rec = PK_d4 + pk_sz(16, 32);              // 16,3  flip
    if (packed) {
        pack_launch(W[1], PK_e0, 16, 32, 0, s);
        pack_launch(W[2], PK_e1, 16, 64, 0, s);
        pack_launch(W[3], PK_e2, 32, 64, 0, s);
        pack_launch(W[4], PK_e3, 32, 128, 0, s);
        pack_launch(W[5], PK_e4, 64, 128, 0, s);
        pack_launch(W[6], PK_d0, 64, 128, 1, s);
        pack_launch(W[8], PK_d2, 32, 64, 1, s);
    }

#define MFMA_CALL(S, F, CI, H, Wd, NTv, in_, wt_, wb_, bi_, out_, co0_, nco_, nhg_) \
    do { if (packed) mfma_launch<S, F, CI, H, Wd, NTv, true, true>(in_, wt_, (const f16x8*)(wb_), bi_, out_, nullptr, COSPLIT_NONE, co0_, nco_, nhg_, s); \
         else        mfma_launch<S, F, CI, H, Wd, NTv, false, true>(in_, wt_, nullptr, bi_, out_, nullptr, COSPLIT_NONE, co0_, nco_, nhg_, s); } while (0)

    fill_k<<<2048, 256, 0, s>>>(P, POOL_UNITS * U);

    f16* FE = P + 32 * U;
    // ---- fe = biqrnn(conv(x)) : 1 -> 48 gates -> 16 ch @256, chunks of 4 ---
    for (int a = 0; a < 16; a += 4) {
        conv_fe_k<<<992, 256, 0, s>>>(x, W[0] + (size_t)a * 27,        B[0] + a,      P);
        conv_fe_k<<<992, 256, 0, s>>>(x, W[0] + (size_t)(16 + a) * 27, B[0] + 16 + a, P + 4 * U);
        conv_fe_k<<<992, 256, 0, s>>>(x, W[0] + (size_t)(32 + a) * 27, B[0] + 32 + a, P + 8 * U);
        pool_launch<true, f16, float, f16>(P, P + 4 * U, P + 12 * U, np, npf, 4, 65536, 0, s);
        pool_launch<true, f16, float, f16>(P, P + 8 * U, FE + (size_t)a * U, P + 12 * U, npf, 4, 65536, 1, s);
    }

    // ---- e0 = qrnn(conv(fe), fwd) : 16 -> 32 -> 16 @256 (MFMA, dual) -------
    f16* E0 = P + 16 * U;
    if (packed) {
        f16* G = P + 48 * U;
        mfma_launch<1, false, 16, 256, 256, 2, true, true>(
            FE, W[1], (const f16x8*)PK_e0, B[1], P, G, 16, 0, 24, 4, s);
        pool_launch<true, f16, float, f16>(P, G, E0, np, npf, 8, 65536, 0, s);
        mfma_launch<1, false, 16, 256, 256, 1, true, true>(
            FE, W[1], (const f16x8*)PK_e0, B[1], G, nullptr, COSPLIT_NONE,
            24, 8, 4, s);
        pool_launch<true, f16, float, f16>(P + 8 * U, G, E0 + 8 * U, np, npf, 8, 65536, 0, s);
    } else {
        MFMA_CALL(1, false, 16, 256, 256, 1, FE, W[1], PK_e0, B[1], P, 0, 16, 4);
        for (int a = 0; a < 16; a += 8) {
            f16* G = P + 48 * U;
            MFMA_CALL(1, false, 16, 256, 256, 1, FE, W[1], PK_e0, B[1], G, 16 + a, 8, 4);
            pool_launch<true, f16, float, f16>(P + (size_t)a * U, G, E0 + (size_t)a * U,
                                               np, npf, 8, 65536, 0, s);
        }
    }
    // FE dead (recomputed later).

    // ---- e1 = qrnn(conv(e0, s2), rev) : 16 -> 64 -> 32 @128 (MFMA) ---------
    f16* E1 = P;
    {
        f16* G = P + 32 * U;
        MFMA_CALL(2, false, 16, 128, 128, 2, E0, W[2], PK_e1, B[2], G, 0, 64, 8);
        pool_launch<true, f16, float, f16>(G, G + 8 * U, E1, np, npf, 32, 16384, 1, s);
    }

    // ---- e2 = qrnn(conv(e1), fwd) : 32 -> 64 -> 32 @128 (MFMA) -------------
    f16* E2 = P + 8 * U;
    {
        f16* G = P + 32 * U;
        MFMA_CALL(1, false, 32, 128, 128, 2, E1, W[3], PK_e2, B[3], G, 0, 64, 8);
        pool_launch<true, f16, float, f16>(G, G + 8 * U, E2, np, npf, 32, 16384, 0, s);
    }

    // ---- e3 = qrnn(conv(e2, s2), rev) : 32 -> 128 -> 64 @64 (MFMA) ---------
    f16* E3 = P + 32 * U;
    {
        f16* G = P + 48 * U;
        MFMA_CALL(2, false, 32, 64, 64, 2, E2, W[4], PK_e3, B[4], G, 0, 128, 16);
        pool_launch<true, f16, float, f16>(G, G + 4 * U, E3, np, npf, 64, 4096, 1, s);
    }

    // ---- e4 = qrnn(conv(e3), fwd) : 64 -> 128 -> 64 @64 (MFMA) -------------
    f16* E4 = P + 40 * U;
    {
        f16* G = P + 48 * U;
        MFMA_CALL(1, false, 64, 64, 64, 2, E3, W[5], PK_e4, B[5], G, 0, 128, 16);
        pool_launch<true, f16, float, f16>(G, G + 4 * U, E4, np, npf, 64, 4096, 0, s);
    }

    // ---- d0 = qrnn(deconv(e4), rev) : 64 -> 128 -> 64 @64 (MFMA, flip) -----
    f16* D0 = P + 44 * U;
    {
        f16* G = P + 48 * U;
        MFMA_CALL(1, true, 64, 64, 64, 2, E4, W[6], PK_d0, B[6], G, 0, 128, 16);
        pool_launch<true, f16, float, f16>(G, G + 4 * U, D0, np, npf, 64, 4096, 1, s);
    }
    // E4 dead. PK_d0 dead -> repack region for d1/d3/d4/rec (stream-ordered).
    if (packed) {
        pack_launch(W[7],  PK_d1, 64, 64, 0, s);
        pack_launch(W[9],  PK_d3, 32, 32, 0, s);
        pack_launch(W[10], PK_d4, 16, 32, 1, s);
        pack_launch(W[11], PK_rec, 16, 3, 1, s);
    }

    // ---- d1 = qrnn(conv(up(d0+e3)), fwd) + e2 : 64 -> 64 -> 32 @128 --------
    // r13: 2 passes. z (co 0-31) -> D1 region [36U,44U) (8U exact) in-place;
    // f (co 32-63) -> G [48U,56U) (8U). Pool 32ch in one go, a1=E2.
    f16* D1 = P + 36 * U;
    if (packed) {
        f16* G = P + 48 * U;
        add_launch(D0, E3, 4 * U, s);
        mfma_up_launch<64, 64, 64, 2>(D0, (const f16x8*)PK_d1, B[7], D1,
                                      nullptr, COSPLIT_NONE, 0, 32, 8, s);
        mfma_up_launch<64, 64, 64, 2>(D0, (const f16x8*)PK_d1, B[7], G,
                                      nullptr, COSPLIT_NONE, 32, 32, 8, s);
        pool_launch<true, f16, float, f16>(D1, G, D1, E2, npf, 32, 16384, 0, s);
    } else {
        for (int a = 0; a < 32; a += 16) {
            f16* G = P + 48 * U;
            conv_up_launch(D0, E3, W[7], B[7], G,         64, a,      16, 64, 64, s);
            conv_up_launch(D0, E3, W[7], B[7], G + 4 * U, 64, 32 + a, 16, 64, 64, s);
            pool_launch<true, f16, float, f16>(G, G + 4 * U, D1 + (size_t)a * V2,
                                               E2 + (size_t)a * V2, npf, 16, 16384, 0, s);
        }
    }
    // E2, E3, D0 dead.

    // ---- d2 = qrnn(deconv(d1), rev) : 32 -> 64 -> 32 @128 (MFMA, flip) -----
    f16* D2 = P + 8 * U;  // over dead E2
    for (int a = 0; a < 32; a += 16) {
        f16* G = P + 48 * U;
        MFMA_CALL(1, true, 32, 128, 128, 1, D1, W[8], PK_d2, B[8], G,         a,      16, 8);
        MFMA_CALL(1, true, 32, 128, 128, 1, D1, W[8], PK_d2, B[8], G + 4 * U, 32 + a, 16, 8);
        pool_launch<true, f16, float, f16>(G, G + 4 * U, D2 + (size_t)a * V2, np, npf, 16, 16384, 1, s);
    }
    // D1 dead.

    // ---- d3 = qrnn(conv(up(d2+e1)), fwd) + e0 : 32 -> 32 -> 16 @256 --------
    // S = D2+E1 in place. Dual calls: call1 co0-23 (z->D3 16U, f16-23->G 8U)
    // + in-place pool a=0; call2 co24-31 -> G + in-place pool a=8.
    f16* D3 = P + 32 * U;  // fresh 16U
    if (packed) {
        f16* G = P + 48 * U;
        add_launch(D2, E1, 8 * U, s);
        mfma_up_launch<32, 128, 128, 2>(D2, (const f16x8*)PK_d3, B[9], D3,
                                        G, 16, 0, 24, 4, s);
        pool_launch<true, f16, float, f16>(D3, G, D3, E0, npf, 8, 65536, 0, s);
        mfma_up_launch<32, 128, 128, 1>(D2, (const f16x8*)PK_d3, B[9], G,
                                        nullptr, COSPLIT_NONE, 24, 8, 4, s);
        pool_launch<true, f16, float, f16>(D3 + 8 * U, G, D3 + 8 * U,
                                           E0 + 8 * U, npf, 8, 65536, 0, s);
    } else {
        for (int a = 0; a < 16; a += 4) {
            f16* G = P + 48 * U;
            conv_up_launch(D2, E1, W[9], B[9], G,         32, a,      4, 128, 128, s);
            conv_up_launch(D2, E1, W[9], B[9], G + 4 * U, 32, 16 + a, 4, 128, 128, s);
            pool_launch<true, f16, float, f16>(G, G + 4 * U, D3 + (size_t)a * U,
                                               E0 + (size_t)a * U, npf, 4, 65536, 0, s);
        }
    }
    // E0, E1, D2 dead.

    // ---- recompute fe -> FE2 = [0,16), gates at [16,32) --------------------
    f16* FE2 = P;
    for (int a = 0; a < 16; a += 4) {
        f16* G = P + 16 * U;
        conv_fe_k<<<992, 256, 0, s>>>(x, W[0] + (size_t)a * 27,        B[0] + a,      G);
        conv_fe_k<<<992, 256, 0, s>>>(x, W[0] + (size_t)(16 + a) * 27, B[0] + 16 + a, G + 4 * U);
        conv_fe_k<<<992, 256, 0, s>>>(x, W[0] + (size_t)(32 + a) * 27, B[0] + 32 + a, G + 8 * U);
        pool_launch<true, f16, float, f16>(G, G + 4 * U, G + 12 * U, np, npf, 4, 65536, 0, s);
        pool_launch<true, f16, float, f16>(G, G + 8 * U, FE2 + (size_t)a * U, G + 12 * U, npf, 4, 65536, 1, s);
    }

    // ---- d4 = qrnn(deconv(d3), rev) + fe : 16 -> 32 -> 16 @256 (dual) ------
    f16* D4 = P + 16 * U;
    if (packed) {
        f16* G = P + 48 * U;
        mfma_launch<1, true, 16, 256, 256, 2, true, true>(
            D3, W[10], (const f16x8*)PK_d4, B[10], D4, G, 16, 0, 24, 4, s);
        pool_launch<true, f16, float, f16>(D4, G, D4, FE2, npf, 8, 65536, 1, s);
        mfma_launch<1, true, 16, 256, 256, 1, true, true>(
            D3, W[10], (const f16x8*)PK_d4, B[10], G, nullptr, COSPLIT_NONE,
            24, 8, 4, s);
        pool_launch<true, f16, float, f16>(D4 + 8 * U, G, D4 + 8 * U,
                                           FE2 + 8 * U, npf, 8, 65536, 1, s);
    } else {
        for (int a = 0; a < 16; a += 4) {
            f16* G = P + 48 * U;
            conv_launch(D3, W[10], B[10], G,         16, a,      4, 256, 256, 256, 256, 1, true, s);
            conv_launch(D3, W[10], B[10], G + 4 * U, 16, 16 + a, 4, 256, 256, 256, 256, 1, true, s);
            pool_launch<true, f16, float, f16>(G, G + 4 * U, D4 + (size_t)a * U,
                                               FE2 + (size_t)a * U, npf, 4, 65536, 1, s);
        }
    }
    // D3, FE2 dead.

    // ---- out = biqrnn(deconv(d4)) + x : 16 -> 3 -> 1 @256 -> fp32 d_out ----
    {
        f16* G = P + 32 * U;   // plain: ch0 z, ch1 f1, ch2 f2 (3U, D3 dead)
        f16* TMP = P + 35 * U;
        if (packed) {
            mfma_launch<1, true, 16, 256, 256, 1, true, false>(
                D4, W[11], (const f16x8*)PK_rec, B[11], G, nullptr, COSPLIT_NONE,
                0, 3, 1, s);
        } else {
            conv_launch(D4, W[11], B[11], G, 16, 0, 3, 256, 256, 256, 256, 1, true, s);
        }
        pool_launch<false, f16, float, f16>(G, G + 1 * U, TMP, np, npf, 1, 65536, 0, s);
        pool_launch<false, f16, float, float>(G, G + 2 * U, out, TMP, x, 1, 65536, 1, s);
    }
#undef MFMA_CALL
}

extern "C" void kernel_launch(void* const* d_in, const int* in_sizes, int n_in,
                              void* d_out, int out_size, void* d_ws, size_t ws_size,
                              hipStream_t stream)
{
    const float* x = (const float*)d_in[0];
    const float* W[12];
    const float* B[12];
    for (int i = 0; i < 12; ++i) {
        W[i] = (const float*)d_in[1 + 2 * i];
        B[i] = (const float*)d_in[2 + 2 * i];
    }

    const size_t need_base = (size_t)(POOL_UNITS * U) * sizeof(f16);     // ~227 MB
    const size_t need_pack = (size_t)(57 * U) * sizeof(f16);             // +~4 MB
    if (ws_size >= need_pack) {
        run_net(x, W, B, (float*)d_out, (f16*)d_ws, true, stream);
    } else if (ws_size >= need_base) {
        run_net(x, W, B, (float*)d_out, (f16*)d_ws, false, stream);
    } else {
        const float ws_mb = (float)((double)ws_size / 1048576.0);
        diag_k<<<(out_size + 255) / 256, 256, 0, stream>>>(
            (float*)d_out, ws_mb, out_size);
    }
}

// Round 14
// 4039.807 us; speedup vs baseline: 1.0648x; 1.0648x over previous
//
#include <hip/hip_runtime.h>
#include <hip/hip_bf16.h>
#include <cstdint>
#include <cstddef>

using f16 = _Float16;
typedef _Float16 f16x2 __attribute__((ext_vector_type(2)));
typedef _Float16 f16x8 __attribute__((ext_vector_type(8)));
typedef float f32x4 __attribute__((ext_vector_type(4)));

static constexpr int DD = 31;                      // depth (time) extent
static constexpr long long U  = 31LL * 256 * 256;  // 2,031,616 elems (1 ch @256)
static constexpr long long V2 = 31LL * 128 * 128;  //   507,904 (1 ch @128)
static constexpr long long POOL_UNITS = 56;        // pool = 56*U f16 elems (~227MB)
static constexpr int CP_CHUNK = 16;                // LDS weight chunk (ci pairs)
static constexpr int COSPLIT_NONE = 1 << 30;

union U32H2 { unsigned u; f16x2 h; };

__device__ __forceinline__ float toF(float v) { return v; }
__device__ __forceinline__ float toF(f16 v) { return (float)v; }
__device__ __forceinline__ void stv(float* p, float v) { *p = v; }
__device__ __forceinline__ void stv(f16* p, float v) { *p = (f16)v; }
__device__ __forceinline__ float sigm(float x) { return 1.f / (1.f + __expf(-x)); }

__device__ __forceinline__ unsigned packh2(float a, float b)
{
    U32H2 r; r.h = f16x2{(f16)a, (f16)b}; return r.u;
}
__device__ __forceinline__ unsigned addh2(unsigned a, unsigned b)
{
    U32H2 x, y, r; x.u = a; y.u = b; r.h = x.h + y.h; return r.u;
}
__device__ __forceinline__ float dot2f(unsigned v, unsigned w, float c)
{
#if __has_builtin(__builtin_amdgcn_fdot2)
    U32H2 uv, uw; uv.u = v; uw.u = w;
    return __builtin_amdgcn_fdot2(uv.h, uw.h, c, false);
#else
    U32H2 uv, uw; uv.u = v; uw.u = w;
    c = fmaf((float)uv.h.x, (float)uw.h.x, c);
    return fmaf((float)uv.h.y, (float)uw.h.y, c);
#endif
}

// ---------------------------------------------------------------------------
__global__ __launch_bounds__(256)
void fill_k(f16* p, long long n)
{
    const long long stride = (long long)gridDim.x * 256;
    for (long long i = (long long)blockIdx.x * 256 + threadIdx.x; i < n; i += stride)
        p[i] = (f16)0.f;
}

// a += b elementwise (f16, 8-wide). Pre-sums skip inputs so the up-conv
// stages ONE tensor (r12: FETCH 382->95MB). Bitwise-identical f16 adds.
__global__ __launch_bounds__(256)
void add_k(f16* __restrict__ a, const f16* __restrict__ b, long long n8)
{
    const long long i = (long long)blockIdx.x * 256 + threadIdx.x;
    if (i >= n8) return;
    uint4 va = ((const uint4*)a)[i];
    const uint4 vb = ((const uint4*)b)[i];
    va.x = addh2(va.x, vb.x); va.y = addh2(va.y, vb.y);
    va.z = addh2(va.z, vb.z); va.w = addh2(va.w, vb.w);
    ((uint4*)a)[i] = va;
}

// ---------------------------------------------------------------------------
// Weight prepack: fp32 [nCo][CIN][27] -> f16x8 MFMA B-fragments, FLIP folded.
// Entry e = ((cc*nhg + hg)*9 + kd*3+Tg)*64 + lane; lane l holds co hg*8+(l&15)
// tap T=Tg*4+(l>>4), elems = 8 ci of chunk cc. nhg = ceil(nCo/8).
// ---------------------------------------------------------------------------
__global__ __launch_bounds__(256)
void pack_w_k(const float* __restrict__ wt, f16* __restrict__ outp,
              int CIN, int nCo, int flip)
{
    const int e = blockIdx.x * 256 + threadIdx.x;
    const int nhg = (nCo + 7) >> 3;
    const int total = (CIN >> 3) * nhg * 9 * 64;
    if (e >= total) return;
    const int l = e & 63;
    const int r = e >> 6;
    const int r9 = r % 9;
    const int t2 = r / 9;
    const int hg = t2 % nhg;
    const int cc = t2 / nhg;
    const int kd = r9 / 3, Tg = r9 - kd * 3;
    const int n = hg * 8 + (l & 15);
    const int T = Tg * 4 + (l >> 4);
    f16x8 bv;
#pragma unroll
    for (int i = 0; i < 8; ++i) bv[i] = (f16)0.f;
    if (T <= 8 && n < nCo) {
        const int kh = T / 3, kw = T - (T / 3) * 3;
        const int st = flip ? ((2 - kd) * 9 + (2 - kh) * 3 + (2 - kw))
                            : (kd * 9 + kh * 3 + kw);
        const size_t wb8 = ((size_t)n * CIN + cc * 8) * 27 + st;
#pragma unroll
        for (int i = 0; i < 8; ++i)
            bv[i] = (f16)wt[wb8 + (size_t)i * 27];
    }
    *(f16x8*)(outp + (size_t)e * 8) = bv;
}

// ---------------------------------------------------------------------------
// MFMA implicit-GEMM conv3d, 3x3x3, pad 1, pair-interleaved in [C/2][D][H][W][2]
// f16. v_mfma_f32_16x16x32_f16. Packed-B register loads issued before the A
// barrier (r9-proven). Dual-output: rel co < coSplit -> out, else outF at
// co-coSplit (both IL). OUTIL=false -> plain [nCo][D][H][W] store (rec).
// Fragment layouts: A row=lane&15, k=(lane>>4)*8+e; B col=lane&15, same k;
// D col=lane&15, row=(lane>>4)*4+reg [m89/m91].
// ---------------------------------------------------------------------------
template<int STRIDE, bool FLIP, int CIN, int HOUT, int WOUT, int NT, bool PACKED,
         bool OUTIL>
__global__ __launch_bounds__(256)
void conv_mfma_k(const f16* __restrict__ in, const float* __restrict__ wt,
                 const f16x8* __restrict__ wb, const float* __restrict__ bias,
                 f16* __restrict__ out, f16* __restrict__ outF, int coSplit,
                 int nCo, int cg0, int nhg)
{
    constexpr int CIC = CIN / 8;
    constexpr int HIN = HOUT * STRIDE, WIN = WOUT * STRIDE;
    constexpr int WT = (WOUT > 128) ? 128 : WOUT;   // 128 or 64
    constexpr int RR = 128 / WT;                    // rows per block
    constexpr int COLS = WOUT / WT;
    constexpr int TPD = (HOUT / RR) * COLS;
    constexpr int AH = STRIDE * (RR - 1) + 3;
    constexpr int AW = STRIDE * (WT - 1) + 3;
    constexpr int APOS = 3 * AH * AW;
    constexpr int NBENT = NT * 576;                 // B entries (fallback)

    extern __shared__ unsigned lds[];
    unsigned* Alds = lds;                           // APOS*4 dwords
    unsigned* Blds = lds + APOS * 4;                // fallback only

    const int tid = threadIdx.x;
    const int l = tid & 63;
    const int wid = tid >> 6;

    const int bx = blockIdx.x;
    const int d0 = bx / TPD;
    const int rem = bx - d0 * TPD;
    const int h0 = (rem / COLS) * RR;
    const int wb_ = (rem % COLS) * WT;

    const int co_base = blockIdx.y * (16 * NT);
    const int nRem = nCo - co_base;
    const int hgBase = cg0 + blockIdx.y * (2 * NT);

    const int base_h = STRIDE * h0 - 1;
    const int base_w = STRIDE * wb_ - 1;
    constexpr size_t HWin = (size_t)HIN * WIN;
    constexpr size_t DHW = (size_t)DD * HWin;       // dwords per channel-pair
    const unsigned* inu = (const unsigned*)in;

    // spatial decode for this lane's two A m-tiles
    int hho[2], wlo[2];
#pragma unroll
    for (int mt = 0; mt < 2; ++mt) {
        const int p = wid * 32 + mt * 16 + (l & 15);
        hho[mt] = p / WT;
        wlo[mt] = p - hho[mt] * WT;
    }
    // lane's tap slot per tap-group
    const int g = l >> 4;
    int khg[3], kwg[3];
#pragma unroll
    for (int Tg = 0; Tg < 3; ++Tg) {
        int T = Tg * 4 + g;
        if (T > 8) T = 8;                           // clamped; B is zero there
        khg[Tg] = T / 3;
        kwg[Tg] = T - (T / 3) * 3;
    }

    f32x4 acc[2][NT];
#pragma unroll
    for (int mt = 0; mt < 2; ++mt)
#pragma unroll
        for (int nt = 0; nt < NT; ++nt)
            acc[mt][nt] = (f32x4){0.f, 0.f, 0.f, 0.f};

    for (int cc = 0; cc < CIC; ++cc) {
        // ---- PACKED: issue B register loads early (latency hides under A) -
        f16x8 bfr[NT][9];
        if (PACKED) {
#pragma unroll
            for (int nt = 0; nt < NT; ++nt)
#pragma unroll
                for (int r9 = 0; r9 < 9; ++r9)
                    bfr[nt][r9] = wb[((size_t)cc * nhg + hgBase + nt * 2) * 9 * 64
                                     + (size_t)r9 * 64 + l];
        }
        __syncthreads();
        // ---- stage A chunk: 4 cp (8 ci) per position ----------------------
        for (int t = tid; t < APOS; t += 256) {
            const int ww = t % AW;
            const int t2 = t / AW;
            const int hh = t2 % AH;
            const int dd = t2 / AH;
            const int d = d0 - 1 + dd;
            const int h = base_h + hh;
            const int w = base_w + ww;
            uint4 val = make_uint4(0u, 0u, 0u, 0u);
            if ((unsigned)d < (unsigned)DD && (unsigned)h < (unsigned)HIN &&
                (unsigned)w < (unsigned)WIN) {
                const size_t gi = (size_t)(cc * 4) * DHW +
                                  (size_t)d * HWin + (size_t)h * WIN + w;
                val.x = inu[gi];
                val.y = inu[gi + DHW];
                val.z = inu[gi + 2 * DHW];
                val.w = inu[gi + 3 * DHW];
            }
            *(uint4*)(Alds + (size_t)t * 4) = val;
        }
        // ---- fallback: stage B fragments via fp32 gather ------------------
        if (!PACKED) {
            for (int t = tid; t < NBENT; t += 256) {
                const int ll = t & 63;
                const int f = t >> 6;
                const int nt = f / 9;
                const int r9 = f - nt * 9;
                const int kd = r9 / 3;
                const int Tg = r9 - kd * 3;
                const int n = nt * 16 + (ll & 15);
                const int gg = ll >> 4;
                const int T = Tg * 4 + gg;
                f16x8 bv;
                if (T <= 8 && n < nRem) {
                    const int kh = T / 3, kw = T - (T / 3) * 3;
                    const int st = FLIP ? ((2 - kd) * 9 + (2 - kh) * 3 + (2 - kw))
                                        : (kd * 9 + kh * 3 + kw);
                    const size_t wb8 = ((size_t)(co_base + n) * CIN + cc * 8) * 27 + st;
#pragma unroll
                    for (int e = 0; e < 8; ++e)
                        bv[e] = (f16)wt[wb8 + (size_t)e * 27];
                } else {
#pragma unroll
                    for (int e = 0; e < 8; ++e) bv[e] = (f16)0.f;
                }
                *(f16x8*)(Blds + (size_t)t * 4) = bv;
            }
        }
        __syncthreads();
        // ---- compute: 3 kd x 3 tap-groups x 2 m-tiles x NT n-tiles --------
#pragma unroll
        for (int kd = 0; kd < 3; ++kd) {
#pragma unroll
            for (int Tg = 0; Tg < 3; ++Tg) {
                f16x8 bfrag[NT];
#pragma unroll
                for (int nt = 0; nt < NT; ++nt)
                    bfrag[nt] = PACKED ? bfr[nt][kd * 3 + Tg]
                                       : *(const f16x8*)
                        (Blds + (size_t)(((nt * 9) + kd * 3 + Tg) * 64 + l) * 4);
                const int kh = khg[Tg], kw = kwg[Tg];
#pragma unroll
                for (int mt = 0; mt < 2; ++mt) {
                    const int hh = STRIDE * hho[mt] + kh;
                    const int ww = STRIDE * wlo[mt] + kw;
                    const f16x8 afrag = *(const f16x8*)
                        (Alds + (size_t)((kd * AH + hh) * AW + ww) * 4);
#pragma unroll
                    for (int nt = 0; nt < NT; ++nt)
                        acc[mt][nt] = __builtin_amdgcn_mfma_f32_16x16x32_f16(
                            afrag, bfrag[nt], acc[mt][nt], 0, 0, 0);
                }
            }
        }
    }

    // ---- store: D lane mapping col(n)=lane&15, row m=(lane>>4)*4+r --------
    const int n = l & 15;
#pragma unroll
    for (int nt = 0; nt < NT; ++nt) {
        const int ng = nt * 16 + n;
        if (ng < nRem) {
            const int co = co_base + ng;
            const float bv = bias[co];
            f16* dst = out;
            int cs = co;
            if (OUTIL && co >= coSplit) { dst = outF; cs = co - coSplit; }
#pragma unroll
            for (int mt = 0; mt < 2; ++mt) {
#pragma unroll
                for (int r = 0; r < 4; ++r) {
                    const int p = wid * 32 + mt * 16 + (l >> 4) * 4 + r;
                    const int hh = p / WT;
                    const int wl = p - hh * WT;
                    const int h = h0 + hh, w = wb_ + wl;
                    const float val = acc[mt][nt][r] + bv;
                    if (OUTIL) {
                        const size_t coPlane =
                            (size_t)(cs >> 1) * DD * HOUT * WOUT * 2 + (cs & 1);
                        dst[coPlane + ((size_t)d0 * HOUT + h) * WOUT * 2 +
                            (size_t)w * 2] = (f16)val;
                    } else {
                        out[((size_t)co * DD + d0) * HOUT * WOUT +
                            (size_t)h * WOUT + w] = (f16)val;
                    }
                }
            }
        }
    }
}

// ---------------------------------------------------------------------------
// MFMA fused conv3d( upsample2x(S) ), stride 1, no flip, IL; S pre-summed.
// r14: REVERTED to the r12 staging (measured best): lo-res halo, padded row
// stride AWLOP, pair-collapsed read iw = ((wpos+kw-1)>>1)+1 (2-lane broadcast,
// 8 entries x 4 banks = 32 banks within a 16-lane group). r13's hi-res
// duplicate staging RAISED conflicts 5.0e7 -> 8.25e7 and dur 327 -> 390us;
// residual conflicts are cross-tap-group row aliasing -- parked. RR=1.
// Dual-output like conv_mfma_k.
// ---------------------------------------------------------------------------
template<int CIN, int HLO, int WLO, int NT>
__global__ __launch_bounds__(256)
void conv_mfma_up_k(const f16* __restrict__ in, const f16x8* __restrict__ wb,
                    const float* __restrict__ bias, f16* __restrict__ out,
                    f16* __restrict__ outF, int coSplit,
                    int nCo, int cg0, int nhg)
{
    constexpr int CIC = CIN / 8;
    constexpr int HOUT = 2 * HLO, WOUT = 2 * WLO;
    constexpr int WT = (WOUT > 128) ? 128 : WOUT;
    constexpr int COLS = WOUT / WT;
    constexpr int TPD = HOUT * COLS;                // RR = 1
    constexpr int AWLO = WT / 2 + 2;
    constexpr int AWLOP = AWLO + 1;                 // padded row stride
    constexpr int APOS = 3 * 2 * AWLO;              // staged entries

    extern __shared__ unsigned lds[];               // 3*2*AWLOP uint4

    const int tid = threadIdx.x;
    const int l = tid & 63;
    const int wid = tid >> 6;

    const int bx = blockIdx.x;
    const int d0 = bx / TPD;
    const int rem = bx - d0 * TPD;
    const int h0 = rem / COLS;
    const int wb_ = (rem % COLS) * WT;

    const int co_base = blockIdx.y * (16 * NT);
    const int nRem = nCo - co_base;
    const int hgBase = cg0 + blockIdx.y * (2 * NT);

    const int rlo0 = (h0 - 1) >> 1;                 // arithmetic shift
    const int clo0 = (wb_ >> 1) - 1;

    constexpr size_t HWlo = (size_t)HLO * WLO;
    constexpr size_t DHW = (size_t)DD * HWlo;
    const unsigned* inu = (const unsigned*)in;

    int wpos[2];
#pragma unroll
    for (int mt = 0; mt < 2; ++mt)
        wpos[mt] = wid * 32 + mt * 16 + (l & 15);

    const int g = l >> 4;
    int khg[3], kwg[3];
#pragma unroll
    for (int Tg = 0; Tg < 3; ++Tg) {
        int T = Tg * 4 + g;
        if (T > 8) T = 8;
        khg[Tg] = T / 3;
        kwg[Tg] = T - (T / 3) * 3;
    }

    f32x4 acc[2][NT];
#pragma unroll
    for (int mt = 0; mt < 2; ++mt)
#pragma unroll
        for (int nt = 0; nt < NT; ++nt)
            acc[mt][nt] = (f32x4){0.f, 0.f, 0.f, 0.f};

    for (int cc = 0; cc < CIC; ++cc) {
        f16x8 bfr[NT][9];
#pragma unroll
        for (int nt = 0; nt < NT; ++nt)
#pragma unroll
            for (int r9 = 0; r9 < 9; ++r9)
                bfr[nt][r9] = wb[((size_t)cc * nhg + hgBase + nt * 2) * 9 * 64
                                 + (size_t)r9 * 64 + l];
        __syncthreads();
        for (int t = tid; t < APOS; t += 256) {
            const int ww = t % AWLO;
            const int t2 = t / AWLO;
            const int rr = t2 & 1;
            const int dd = t2 >> 1;
            const int d = d0 - 1 + dd;
            const int hlo = rlo0 + rr;
            const int wlo = clo0 + ww;
            uint4 val = make_uint4(0u, 0u, 0u, 0u);
            if ((unsigned)d < (unsigned)DD && (unsigned)hlo < (unsigned)HLO &&
                (unsigned)wlo < (unsigned)WLO) {
                const size_t gi = (size_t)(cc * 4) * DHW +
                                  (size_t)d * HWlo + (size_t)hlo * WLO + wlo;
                val.x = inu[gi];
                val.y = inu[gi + DHW];
                val.z = inu[gi + 2 * DHW];
                val.w = inu[gi + 3 * DHW];
            }
            *(uint4*)(lds + (size_t)((dd * 2 + rr) * AWLOP + ww) * 4) = val;
        }
        __syncthreads();
#pragma unroll
        for (int kd = 0; kd < 3; ++kd) {
#pragma unroll
            for (int Tg = 0; Tg < 3; ++Tg) {
                const int kh = khg[Tg], kw = kwg[Tg];
                const int rr = ((h0 + kh - 1) >> 1) - rlo0;   // 0 or 1
#pragma unroll
                for (int mt = 0; mt < 2; ++mt) {
                    const int iw = ((wpos[mt] + kw - 1) >> 1) + 1;
                    const f16x8 afrag = *(const f16x8*)
                        (lds + (size_t)((kd * 2 + rr) * AWLOP + iw) * 4);
#pragma unroll
                    for (int nt = 0; nt < NT; ++nt)
                        acc[mt][nt] = __builtin_amdgcn_mfma_f32_16x16x32_f16(
                            afrag, bfr[nt][kd * 3 + Tg], acc[mt][nt], 0, 0, 0);
                }
            }
        }
    }

    const int n = l & 15;
#pragma unroll
    for (int nt = 0; nt < NT; ++nt) {
        const int ng = nt * 16 + n;
        if (ng < nRem) {
            const int co = co_base + ng;
            const float bv = bias[co];
            f16* dst = out;
            int cs = co;
            if (co >= coSplit) { dst = outF; cs = co - coSplit; }
            const size_t coPlane = (size_t)(cs >> 1) * DD * HOUT * WOUT * 2 + (cs & 1);
#pragma unroll
            for (int mt = 0; mt < 2; ++mt) {
#pragma unroll
                for (int r = 0; r < 4; ++r) {
                    const int p = wid * 32 + mt * 16 + (l >> 4) * 4 + r;
                    dst[coPlane + ((size_t)d0 * HOUT + h0) * WOUT * 2 +
                        (size_t)(wb_ + p) * 2] = (f16)(acc[mt][nt][r] + bv);
                }
            }
        }
    }
}

// ---------------------------------------------------------------------------
// Scalar pair-interleaved direct conv3d (fallback only). W-tile 8, dot2.
// ---------------------------------------------------------------------------
template<int STRIDE, bool FLIP, int CO_BLK, bool OUT_IL>
__global__ __launch_bounds__(256, 2)
void conv3d_il_k(const f16* __restrict__ in, const float* __restrict__ wt,
                 const float* __restrict__ bias, f16* __restrict__ out,
                 int Cin, int Hin, int Win, int Hout, int Wout)
{
    extern __shared__ unsigned wl2[];  // [CP_CHUNK*27][CO_BLK]
    const int co_base = blockIdx.y * CO_BLK;

    const int s8 = (blockIdx.x * 256 + threadIdx.x) * 8;
    const int w0 = s8 % Wout;
    const int sh = s8 / Wout;
    const int h0 = sh % Hout;
    const int d0 = sh / Hout;

    float acc[CO_BLK][8];
#pragma unroll
    for (int j = 0; j < CO_BLK; ++j) {
        const float bv = bias[co_base + j];
#pragma unroll
        for (int o = 0; o < 8; ++o) acc[j][o] = bv;
    }

    const size_t HWin = (size_t)Hin * Win;
    const int CP = Cin >> 1;

    for (int cp0 = 0; cp0 < CP; cp0 += CP_CHUNK) {
        const int cnp = (CP - cp0 < CP_CHUNK) ? (CP - cp0) : CP_CHUNK;
        __syncthreads();
        for (int t = threadIdx.x; t < cnp * 27 * CO_BLK; t += 256) {
            const int j = t % CO_BLK;
            const int k = (t / CO_BLK) % 27;
            const int cp = t / (CO_BLK * 27);
            int src;
            if (FLIP) {
                const int kd = k / 9, kh = (k / 3) % 3, kw = k % 3;
                src = (2 - kd) * 9 + (2 - kh) * 3 + (2 - kw);
            } else {
                src = k;
            }
            const int ci = (cp0 + cp) * 2;
            const size_t wb = (size_t)(co_base + j) * Cin;
            wl2[t] = packh2(wt[(wb + ci) * 27 + src], wt[(wb + ci + 1) * 27 + src]);
        }
        __syncthreads();

        for (int cp = 0; cp < cnp; ++cp) {
            const f16* cb = in + (size_t)(cp0 + cp) * DD * HWin * 2;
            const unsigned* wc = wl2 + cp * 27 * CO_BLK;
#pragma unroll
            for (int kd = 0; kd < 3; ++kd) {
                const int di = d0 + kd - 1;
                if (di < 0 || di >= DD) continue;
#pragma unroll
                for (int kh = 0; kh < 3; ++kh) {
                    const int hi = h0 * STRIDE + kh - 1;
                    if (hi < 0 || hi >= Hin) continue;
                    const unsigned* rowu = (const unsigned*)
                        (cb + ((size_t)di * HWin + (size_t)hi * Win) * 2);
                    if (STRIDE == 1) {
                        unsigned v2[10];
                        v2[0] = (w0 > 0) ? rowu[w0 - 1] : 0u;
                        const uint4 q1 = *(const uint4*)(rowu + w0);
                        const uint4 q2 = *(const uint4*)(rowu + w0 + 4);
                        v2[1] = q1.x; v2[2] = q1.y; v2[3] = q1.z; v2[4] = q1.w;
                        v2[5] = q2.x; v2[6] = q2.y; v2[7] = q2.z; v2[8] = q2.w;
                        v2[9] = (w0 + 8 < Win) ? rowu[w0 + 8] : 0u;
                        const unsigned* wk = wc + (kd * 9 + kh * 3) * CO_BLK;
#pragma unroll
                        for (int kw = 0; kw < 3; ++kw) {
#pragma unroll
                            for (int j = 0; j < CO_BLK; ++j) {
                                const unsigned wv = wk[kw * CO_BLK + j];
#pragma unroll
                                for (int o = 0; o < 8; ++o)
                                    acc[j][o] = dot2f(v2[o + kw], wv, acc[j][o]);
                            }
                        }
                    } else {
                        unsigned v2[17];
                        const int p0 = w0 * 2;
                        v2[0] = (w0 > 0) ? rowu[p0 - 1] : 0u;
#pragma unroll
                        for (int q = 0; q < 4; ++q) {
                            const uint4 qq = *(const uint4*)(rowu + p0 + 4 * q);
                            v2[1 + 4 * q] = qq.x; v2[2 + 4 * q] = qq.y;
                            v2[3 + 4 * q] = qq.z; v2[4 + 4 * q] = qq.w;
                        }
                        const unsigned* wk = wc + (kd * 9 + kh * 3) * CO_BLK;
#pragma unroll
                        for (int kw = 0; kw < 3; ++kw) {
#pragma unroll
                            for (int j = 0; j < CO_BLK; ++j) {
                                const unsigned wv = wk[kw * CO_BLK + j];
#pragma unroll
                                for (int o = 0; o < 8; ++o)
                                    acc[j][o] = dot2f(v2[2 * o + kw], wv, acc[j][o]);
                            }
                        }
                    }
                }
            }
        }
    }

    if (OUT_IL) {
#pragma unroll
        for (int pj = 0; pj < CO_BLK / 2; ++pj) {
            f16* op = out + ((((size_t)((co_base >> 1) + pj) * DD + d0) * Hout + h0)
                             * Wout + w0) * 2;
            unsigned dw[8];
#pragma unroll
            for (int o = 0; o < 8; ++o)
                dw[o] = packh2(acc[2 * pj][o], acc[2 * pj + 1][o]);
            *(uint4*)op = make_uint4(dw[0], dw[1], dw[2], dw[3]);
            *(uint4*)(op + 8) = make_uint4(dw[4], dw[5], dw[6], dw[7]);
        }
    } else {
#pragma unroll
        for (int j = 0; j < CO_BLK; ++j) {
            f16* op = out + (((size_t)(co_base + j) * DD + d0) * Hout + h0) * Wout + w0;
            unsigned dw[4];
#pragma unroll
            for (int o = 0; o < 4; ++o)
                dw[o] = packh2(acc[j][2 * o], acc[j][2 * o + 1]);
            *(uint4*)op = make_uint4(dw[0], dw[1], dw[2], dw[3]);
        }
    }
}

// ---------------------------------------------------------------------------
// Scalar fused conv3d( upsample2x(a + b) ) (fallback only).
// ---------------------------------------------------------------------------
template<int CO_BLK>
__global__ __launch_bounds__(256, 2)
void conv3d_up_il_k(const f16* __restrict__ ia, const f16* __restrict__ ib,
                    const float* __restrict__ wt, const float* __restrict__ bias,
                    f16* __restrict__ out, int Cin, int Hlo, int Wlo)
{
    extern __shared__ unsigned wl2[];
    const int co_base = blockIdx.y * CO_BLK;

    const int Hout = 2 * Hlo, Wout = 2 * Wlo;
    const int s8 = (blockIdx.x * 256 + threadIdx.x) * 8;
    const int w0 = s8 % Wout;
    const int sh = s8 / Wout;
    const int h0 = sh % Hout;
    const int d0 = sh / Hout;
    const int lw = w0 >> 1;  // multiple of 4

    float acc[CO_BLK][8];
#pragma unroll
    for (int j = 0; j < CO_BLK; ++j) {
        const float bv = bias[co_base + j];
#pragma unroll
        for (int o = 0; o < 8; ++o) acc[j][o] = bv;
    }
    const size_t HWlo = (size_t)Hlo * Wlo;
    const int CP = Cin >> 1;

    for (int cp0 = 0; cp0 < CP; cp0 += CP_CHUNK) {
        const int cnp = (CP - cp0 < CP_CHUNK) ? (CP - cp0) : CP_CHUNK;
        __syncthreads();
        for (int t = threadIdx.x; t < cnp * 27 * CO_BLK; t += 256) {
            const int j = t % CO_BLK;
            const int k = (t / CO_BLK) % 27;
            const int cp = t / (CO_BLK * 27);
            const int ci = (cp0 + cp) * 2;
            const size_t wb = (size_t)(co_base + j) * Cin;
            wl2[t] = packh2(wt[(wb + ci) * 27 + k], wt[(wb + ci + 1) * 27 + k]);
        }
        __syncthreads();

        for (int cp = 0; cp < cnp; ++cp) {
            const f16* cba = ia + (size_t)(cp0 + cp) * DD * HWlo * 2;
            const f16* cbb = ib + (size_t)(cp0 + cp) * DD * HWlo * 2;
            const unsigned* wc = wl2 + cp * 27 * CO_BLK;
#pragma unroll
            for (int kd = 0; kd < 3; ++kd) {
                const int di = d0 + kd - 1;
                if (di < 0 || di >= DD) continue;
#pragma unroll
                for (int kh = 0; kh < 3; ++kh) {
                    const int hi = h0 + kh - 1;
                    if (hi < 0 || hi >= Hout) continue;
                    const int hlo = hi >> 1;
                    const unsigned* rua = (const unsigned*)
                        (cba + ((size_t)di * HWlo + (size_t)hlo * Wlo) * 2);
                    const unsigned* rub = (const unsigned*)
                        (cbb + ((size_t)di * HWlo + (size_t)hlo * Wlo) * 2);
                    unsigned u[6];
                    u[0] = (lw > 0) ? addh2(rua[lw - 1], rub[lw - 1]) : 0u;
                    const uint4 qa = *(const uint4*)(rua + lw);
                    const uint4 qb = *(const uint4*)(rub + lw);
                    u[1] = addh2(qa.x, qb.x); u[2] = addh2(qa.y, qb.y);
                    u[3] = addh2(qa.z, qb.z); u[4] = addh2(qa.w, qb.w);
                    u[5] = (lw + 4 < Wlo) ? addh2(rua[lw + 4], rub[lw + 4]) : 0u;
                    // upsampled window: up-w = w0-1+t, t in [0,10)
                    const unsigned v2[10] = { u[0], u[1], u[1], u[2], u[2],
                                              u[3], u[3], u[4], u[4], u[5] };
                    const unsigned* wk = wc + (kd * 9 + kh * 3) * CO_BLK;
#pragma unroll
                    for (int kw = 0; kw < 3; ++kw) {
#pragma unroll
                        for (int j = 0; j < CO_BLK; ++j) {
                            const unsigned wv = wk[kw * CO_BLK + j];
#pragma unroll
                            for (int o = 0; o < 8; ++o)
                                acc[j][o] = dot2f(v2[o + kw], wv, acc[j][o]);
                        }
                    }
                }
            }
        }
    }
#pragma unroll
    for (int pj = 0; pj < CO_BLK / 2; ++pj) {
        f16* op = out + ((((size_t)((co_base >> 1) + pj) * DD + d0) * Hout + h0)
                         * Wout + w0) * 2;
        unsigned dw[8];
#pragma unroll
        for (int o = 0; o < 8; ++o)
            dw[o] = packh2(acc[2 * pj][o], acc[2 * pj + 1][o]);
        *(uint4*)op = make_uint4(dw[0], dw[1], dw[2], dw[3]);
        *(uint4*)(op + 8) = make_uint4(dw[4], dw[5], dw[6], dw[7]);
    }
}

// ---------------------------------------------------------------------------
// fe conv: Cin=1, fp32 plain input x, interleaved f16 out (CO_BLK=4). @256^2.
// ---------------------------------------------------------------------------
__global__ __launch_bounds__(256, 2)
void conv_fe_k(const float* __restrict__ in, const float* __restrict__ wt,
               const float* __restrict__ bias, f16* __restrict__ out)
{
    __shared__ float wl[27 * 4];
    for (int t = threadIdx.x; t < 27 * 4; t += 256) {
        const int j = t % 4;
        const int k = t / 4;
        wl[t] = wt[(size_t)j * 27 + k];
    }
    __syncthreads();

    const int W = 256, H = 256;
    const int s8 = (blockIdx.x * 256 + threadIdx.x) * 8;
    const int w0 = s8 % W;
    const int sh = s8 / W;
    const int h0 = sh % H;
    const int d0 = sh / H;

    float acc[4][8];
#pragma unroll
    for (int j = 0; j < 4; ++j) {
        const float bv = bias[j];
#pragma unroll
        for (int o = 0; o < 8; ++o) acc[j][o] = bv;
    }
    const size_t HW = 65536;

#pragma unroll
    for (int kd = 0; kd < 3; ++kd) {
        const int di = d0 + kd - 1;
        if (di < 0 || di >= DD) continue;
#pragma unroll
        for (int kh = 0; kh < 3; ++kh) {
            const int hi = h0 + kh - 1;
            if (hi < 0 || hi >= H) continue;
            const float* row = in + (size_t)di * HW + (size_t)hi * W + w0;
            float v[10];
            v[0] = (w0 > 0) ? row[-1] : 0.f;
            const float4 q1 = *(const float4*)row;
            const float4 q2 = *(const float4*)(row + 4);
            v[1] = q1.x; v[2] = q1.y; v[3] = q1.z; v[4] = q1.w;
            v[5] = q2.x; v[6] = q2.y; v[7] = q2.z; v[8] = q2.w;
            v[9] = (w0 + 8 < W) ? row[8] : 0.f;
            const float* wk = wl + (kd * 9 + kh * 3) * 4;
#pragma unroll
            for (int kw = 0; kw < 3; ++kw) {
#pragma unroll
                for (int j = 0; j < 4; ++j) {
                    const float wv = wk[kw * 4 + j];
#pragma unroll
                    for (int o = 0; o < 8; ++o)
                        acc[j][o] = fmaf(v[o + kw], wv, acc[j][o]);
                }
            }
        }
    }
#pragma unroll
    for (int pj = 0; pj < 2; ++pj) {
        f16* op = out + (((size_t)pj * DD + d0) * H + h0) * (size_t)W * 2 + (size_t)w0 * 2;
        unsigned dw[8];
#pragma unroll
        for (int o = 0; o < 8; ++o)
            dw[o] = packh2(acc[2 * pj][o], acc[2 * pj + 1][o]);
        *(uint4*)op = make_uint4(dw[0], dw[1], dw[2], dw[3]);
        *(uint4*)(op + 8) = make_uint4(dw[4], dw[5], dw[6], dw[7]);
    }
}

// ---------------------------------------------------------------------------
// fo_pool over D=31. IL=true: pair-interleaved [C/2][D][HW][2]; else plain
// [C][D][HW]. out = h_d + a1? + a2?  In-place (out==z) is safe.
// ---------------------------------------------------------------------------
template<bool IL, typename TA1, typename TA2, typename TO>
__global__ __launch_bounds__(256)
void fo_pool_k(const f16* __restrict__ z, const f16* __restrict__ f,
               TO* __restrict__ out, const TA1* __restrict__ a1,
               const TA2* __restrict__ a2, int C, int HW, int reverse)
{
    const long long idx = (long long)blockIdx.x * 256 + threadIdx.x;
    if (idx >= (long long)C * HW) return;
    size_t base; size_t step;
    if (IL) {
        const long long pairIdx = idx / (2LL * HW);
        const int rem = (int)(idx - pairIdx * 2LL * HW);
        const int p = rem >> 1;
        const int par = rem & 1;
        base = ((size_t)pairIdx * DD * HW + p) * 2 + par;
        step = (size_t)HW * 2;
    } else {
        const int c = (int)(idx / HW);
        const int p = (int)(idx - (long long)c * HW);
        base = (size_t)c * DD * HW + p;
        step = (size_t)HW;
    }
    float h = 0.f;
    if (!reverse) {
        for (int d = 0; d < DD; ++d) {
            const size_t off = base + (size_t)d * step;
            const float zz = tanhf(toF(z[off]));
            const float ff = sigm(toF(f[off]));
            h = ff * h + (1.f - ff) * zz;
            float v = h;
            if (a1) v += toF(a1[off]);
            if (a2) v += toF(a2[off]);
            stv(out + off, v);
        }
    } else {
        for (int d = DD - 1; d >= 0; --d) {
            const size_t off = base + (size_t)d * step;
            const float zz = tanhf(toF(z[off]));
            const float ff = sigm(toF(f[off]));
            h = ff * h + (1.f - ff) * zz;
            float v = h;
            if (a1) v += toF(a1[off]);
            if (a2) v += toF(a2[off]);
            stv(out + off, v);
        }
    }
}

// Diagnostic: encode ws_size (MB) into output if workspace too small.
__global__ __launch_bounds__(256)
void diag_k(float* out, float v, int n)
{
    const int i = blockIdx.x * 256 + threadIdx.x;
    if (i < n) out[i] = v;
}

// ---------------------------------------------------------------------------

template<int STRIDE, bool FLIP, int CIN, int HOUT, int WOUT, int NT, bool PACKED,
         bool OUTIL>
static inline void mfma_launch(const f16* in, const float* w, const f16x8* wb,
                               const float* b, f16* out, f16* outF, int coSplit,
                               int co0, int nCo, int nhg, hipStream_t s)
{
    constexpr int WT = WOUT > 128 ? 128 : WOUT;
    constexpr int RR = 128 / WT;
    constexpr int AH = STRIDE * (RR - 1) + 3;
    constexpr int AW = STRIDE * (WT - 1) + 3;
    constexpr size_t lds = (size_t)(3 * AH * AW) * 16 +
                           (PACKED ? 0 : (size_t)NT * 9216);
    dim3 grid((unsigned)(DD * (HOUT / RR) * (WOUT / WT)),
              (unsigned)((nCo + 16 * NT - 1) / (16 * NT)));
    conv_mfma_k<STRIDE, FLIP, CIN, HOUT, WOUT, NT, PACKED, OUTIL>
        <<<grid, 256, lds, s>>>(
        in, w + (size_t)co0 * CIN * 27, wb, b + co0, out, outF, coSplit,
        nCo, co0 / 8, nhg);
}

template<int CIN, int HLO, int WLO, int NT>
static inline void mfma_up_launch(const f16* in, const f16x8* wb,
                                  const float* b, f16* out, f16* outF,
                                  int coSplit, int co0, int nCo,
                                  int nhg, hipStream_t s)
{
    constexpr int WOUT = 2 * WLO;
    constexpr int WT = WOUT > 128 ? 128 : WOUT;
    constexpr int AWLOP = WT / 2 + 3;
    constexpr size_t lds = (size_t)(3 * 2 * AWLOP) * 16;
    dim3 grid((unsigned)(DD * (2 * HLO) * (WOUT / WT)),
              (unsigned)((nCo + 16 * NT - 1) / (16 * NT)));
    conv_mfma_up_k<CIN, HLO, WLO, NT><<<grid, 256, lds, s>>>(
        in, wb, b + co0, out, outF, coSplit, nCo, co0 / 8, nhg);
}

static inline void conv_launch(const f16* in, const float* w, const float* b,
                               f16* out, int Cin, int co0, int nCo,
                               int Hin, int Win, int Hout, int Wout,
                               int stride, bool flip, hipStream_t s)
{
    const unsigned gx = (unsigned)((DD * (long long)Hout * Wout) / 2048);
    const float* wp = w + (size_t)co0 * Cin * 27;
    const float* bp = b + co0;
    const int cpc = (Cin / 2 < CP_CHUNK) ? Cin / 2 : CP_CHUNK;
    if (flip) {
        if (nCo % 4 == 0) {
            dim3 grid(gx, nCo / 4);
            conv3d_il_k<1, true, 4, true><<<grid, 256, (size_t)cpc * 27 * 4 * 4, s>>>(
                in, wp, bp, out, Cin, Hin, Win, Hout, Wout);
        } else {  // rec layer: nCo == 3, plain output
            dim3 grid(gx, 1);
            conv3d_il_k<1, true, 3, false><<<grid, 256, (size_t)cpc * 27 * 3 * 4, s>>>(
                in, wp, bp, out, Cin, Hin, Win, Hout, Wout);
        }
    } else {
        dim3 grid(gx, nCo / 8);
        conv3d_il_k<1, false, 8, true><<<grid, 256, (size_t)cpc * 27 * 8 * 4, s>>>(
            in, wp, bp, out, Cin, Hin, Win, Hout, Wout);
    }
}

static inline void conv_up_launch(const f16* ia, const f16* ib, const float* w,
                                  const float* b, f16* out, int Cin, int co0,
                                  int nCo, int Hlo, int Wlo, hipStream_t s)
{
    const unsigned gx = (unsigned)((DD * 4LL * Hlo * Wlo) / 2048);
    const int cpc = (Cin / 2 < CP_CHUNK) ? Cin / 2 : CP_CHUNK;
    if (nCo % 8 == 0) {
        dim3 grid(gx, nCo / 8);
        conv3d_up_il_k<8><<<grid, 256, (size_t)cpc * 27 * 8 * 4, s>>>(
            ia, ib, w + (size_t)co0 * Cin * 27, b + co0, out, Cin, Hlo, Wlo);
    } else {
        dim3 grid(gx, nCo / 4);
        conv3d_up_il_k<4><<<grid, 256, (size_t)cpc * 27 * 4 * 4, s>>>(
            ia, ib, w + (size_t)co0 * Cin * 27, b + co0, out, Cin, Hlo, Wlo);
    }
}

template<bool IL, typename TA1, typename TA2, typename TO>
static inline void pool_launch(const f16* z, const f16* f, TO* o, const TA1* a1,
                               const TA2* a2, int C, int HW, int rev,
                               hipStream_t s)
{
    const long long tot = (long long)C * HW;
    fo_pool_k<IL, TA1, TA2, TO><<<(unsigned)((tot + 255) / 256), 256, 0, s>>>(
        z, f, o, a1, a2, C, HW, rev);
}

static inline void pack_launch(const float* w, f16* outp, int CIN, int nCo,
                               int flip, hipStream_t s)
{
    const int total = (CIN / 8) * ((nCo + 7) / 8) * 9 * 64;
    pack_w_k<<<(total + 255) / 256, 256, 0, s>>>(w, outp, CIN, nCo, flip);
}

static inline void add_launch(f16* a, const f16* b, long long n, hipStream_t s)
{
    const long long n8 = n / 8;
    add_k<<<(unsigned)((n8 + 255) / 256), 256, 0, s>>>(a, b, n8);
}

// pack sizes in f16 elems (ceil co groups)
static constexpr size_t pk_sz(int CIN, int nCo)
{ return (size_t)(CIN / 8) * ((nCo + 7) / 8) * 9 * 64 * 8; }

// ---------------------------------------------------------------------------
// Memory plan (units of U). Pool = 56 U f16; packed weights (<1U) at 56U.
// r14: (1) up-kernel staging reverted to r12 (measured best); (2) d2 now
// 2 passes (z co0-31 -> D2 [8U,16U) exact, in-place pool; f co32-63 -> G);
// (3) if ws_size >= 74U*2B, FE saved at [57U,73U) and fe recompute skipped.
// All write extents audited against slots (r10 lesson).
// ---------------------------------------------------------------------------
static void run_net(const float* x, const float* const* W, const float* const* B,
                    float* out, f16* P, bool packed, bool saveFE, hipStream_t s)
{
    const f16* np = nullptr;
    const float* npf = nullptr;

    // ---- packed-weight buffers at P + 56U ----------------------------------
    f16* WP = P + 56 * U;
    f16* PK_e0 = WP;                                  // 16,32
    f16* PK_e1 = PK_e0 + pk_sz(16, 32);               // 16,64
    f16* PK_e2 = PK_e1 + pk_sz(16, 64);               // 32,64
    f16* PK_e3 = PK_e2 + pk_sz(32, 64);               // 32,128
    f16* PK_e4 = PK_e3 + pk_sz(32, 128);              // 64,128
    f16* PK_d0 = PK_e4 + pk_sz(64, 128);              // 64,128 flip
    f16* PK_d2 = PK_d0 + pk_sz(64, 128);              // 32,64 flip
    // late packs reuse PK_d0's region (dead after d0 conv):
    f16* PK_d1 = PK_d0;                               // 64,64
    f16* PK_d3 = PK_d1 + pk_sz(64, 64);               // 32,32
    f16* PK_d4 = PK_d3 + pk_sz(32, 32);               // 16,32 flip
    f16* PK_rec = PK_d4 + pk_sz(16, 32);              // 16,3  flip
    if (packed) {
        pack_launch(W[1], PK_e0, 16, 32, 0, s);
        pack_launch(W[2], PK_e1, 16, 64, 0, s);
        pack_launch(W[3], PK_e2, 32, 64, 0, s);
        pack_launch(W[4], PK_e3, 32, 128, 0, s);
        pack_launch(W[5], PK_e4, 64, 128, 0, s);
        pack_launch(W[6], PK_d0, 64, 128, 1, s);
        pack_launch(W[8], PK_d2, 32, 64, 1, s);
    }

#define MFMA_CALL(S, F, CI, H, Wd, NTv, in_, wt_, wb_, bi_, out_, co0_, nco_, nhg_) \
    do { if (packed) mfma_launch<S, F, CI, H, Wd, NTv, true, true>(in_, wt_, (const f16x8*)(wb_), bi_, out_, nullptr, COSPLIT_NONE, co0_, nco_, nhg_, s); \
         else        mfma_launch<S, F, CI, H, Wd, NTv, false, true>(in_, wt_, nullptr, bi_, out_, nullptr, COSPLIT_NONE, co0_, nco_, nhg_, s); } while (0)

    fill_k<<<2048, 256, 0, s>>>(P, POOL_UNITS * U);

    // FE location: extended slot [57U,73U) if saveFE (skips recompute), else
    // the classic [32U,48U) slot (overwritten by e3/e4/d0 -> recompute later).
    f16* FE = saveFE ? (P + 57 * U) : (P + 32 * U);
    // ---- fe = biqrnn(conv(x)) : 1 -> 48 gates -> 16 ch @256, chunks of 4 ---
    for (int a = 0; a < 16; a += 4) {
        conv_fe_k<<<992, 256, 0, s>>>(x, W[0] + (size_t)a * 27,        B[0] + a,      P);
        conv_fe_k<<<992, 256, 0, s>>>(x, W[0] + (size_t)(16 + a) * 27, B[0] + 16 + a, P + 4 * U);
        conv_fe_k<<<992, 256, 0, s>>>(x, W[0] + (size_t)(32 + a) * 27, B[0] + 32 + a, P + 8 * U);
        pool_launch<true, f16, float, f16>(P, P + 4 * U, P + 12 * U, np, npf, 4, 65536, 0, s);
        pool_launch<true, f16, float, f16>(P, P + 8 * U, FE + (size_t)a * U, P + 12 * U, npf, 4, 65536, 1, s);
    }

    // ---- e0 = qrnn(conv(fe), fwd) : 16 -> 32 -> 16 @256 (MFMA, dual) -------
    f16* E0 = P + 16 * U;
    if (packed) {
        f16* G = P + 48 * U;
        mfma_launch<1, false, 16, 256, 256, 2, true, true>(
            FE, W[1], (const f16x8*)PK_e0, B[1], P, G, 16, 0, 24, 4, s);
        pool_launch<true, f16, float, f16>(P, G, E0, np, npf, 8, 65536, 0, s);
        mfma_launch<1, false, 16, 256, 256, 1, true, true>(
            FE, W[1], (const f16x8*)PK_e0, B[1], G, nullptr, COSPLIT_NONE,
            24, 8, 4, s);
        pool_launch<true, f16, float, f16>(P + 8 * U, G, E0 + 8 * U, np, npf, 8, 65536, 0, s);
    } else {
        MFMA_CALL(1, false, 16, 256, 256, 1, FE, W[1], PK_e0, B[1], P, 0, 16, 4);
        for (int a = 0; a < 16; a += 8) {
            f16* G = P + 48 * U;
            MFMA_CALL(1, false, 16, 256, 256, 1, FE, W[1], PK_e0, B[1], G, 16 + a, 8, 4);
            pool_launch<true, f16, float, f16>(P + (size_t)a * U, G, E0 + (size_t)a * U,
                                               np, npf, 8, 65536, 0, s);
        }
    }
    // FE dead here unless saveFE.

    // ---- e1 = qrnn(conv(e0, s2), rev) : 16 -> 64 -> 32 @128 (MFMA) ---------
    f16* E1 = P;
    {
        f16* G = P + 32 * U;
        MFMA_CALL(2, false, 16, 128, 128, 2, E0, W[2], PK_e1, B[2], G, 0, 64, 8);
        pool_launch<true, f16, float, f16>(G, G + 8 * U, E1, np, npf, 32, 16384, 1, s);
    }

    // ---- e2 = qrnn(conv(e1), fwd) : 32 -> 64 -> 32 @128 (MFMA) -------------
    f16* E2 = P + 8 * U;
    {
        f16* G = P + 32 * U;
        MFMA_CALL(1, false, 32, 128, 128, 2, E1, W[3], PK_e2, B[3], G, 0, 64, 8);
        pool_launch<true, f16, float, f16>(G, G + 8 * U, E2, np, npf, 32, 16384, 0, s);
    }

    // ---- e3 = qrnn(conv(e2, s2), rev) : 32 -> 128 -> 64 @64 (MFMA) ---------
    f16* E3 = P + 32 * U;
    {
        f16* G = P + 48 * U;
        MFMA_CALL(2, false, 32, 64, 64, 2, E2, W[4], PK_e3, B[4], G, 0, 128, 16);
        pool_launch<true, f16, float, f16>(G, G + 4 * U, E3, np, npf, 64, 4096, 1, s);
    }

    // ---- e4 = qrnn(conv(e3), fwd) : 64 -> 128 -> 64 @64 (MFMA) -------------
    f16* E4 = P + 40 * U;
    {
        f16* G = P + 48 * U;
        MFMA_CALL(1, false, 64, 64, 64, 2, E3, W[5], PK_e4, B[5], G, 0, 128, 16);
        pool_launch<true, f16, float, f16>(G, G + 4 * U, E4, np, npf, 64, 4096, 0, s);
    }

    // ---- d0 = qrnn(deconv(e4), rev) : 64 -> 128 -> 64 @64 (MFMA, flip) -----
    f16* D0 = P + 44 * U;
    {
        f16* G = P + 48 * U;
        MFMA_CALL(1, true, 64, 64, 64, 2, E4, W[6], PK_d0, B[6], G, 0, 128, 16);
        pool_launch<true, f16, float, f16>(G, G + 4 * U, D0, np, npf, 64, 4096, 1, s);
    }
    // E4 dead. PK_d0 dead -> repack region for d1/d3/d4/rec (stream-ordered).
    if (packed) {
        pack_launch(W[7],  PK_d1, 64, 64, 0, s);
        pack_launch(W[9],  PK_d3, 32, 32, 0, s);
        pack_launch(W[10], PK_d4, 16, 32, 1, s);
        pack_launch(W[11], PK_rec, 16, 3, 1, s);
    }

    // ---- d1 = qrnn(conv(up(d0+e3)), fwd) + e2 : 64 -> 64 -> 32 @128 --------
    // 2 passes. z (co 0-31) -> D1 region [36U,44U) (8U exact) in-place;
    // f (co 32-63) -> G [48U,56U) (8U). Pool 32ch in one go, a1=E2.
    f16* D1 = P + 36 * U;
    if (packed) {
        f16* G = P + 48 * U;
        add_launch(D0, E3, 4 * U, s);
        mfma_up_launch<64, 64, 64, 2>(D0, (const f16x8*)PK_d1, B[7], D1,
                                      nullptr, COSPLIT_NONE, 0, 32, 8, s);
        mfma_up_launch<64, 64, 64, 2>(D0, (const f16x8*)PK_d1, B[7], G,
                                      nullptr, COSPLIT_NONE, 32, 32, 8, s);
        pool_launch<true, f16, float, f16>(D1, G, D1, E2, npf, 32, 16384, 0, s);
    } else {
        for (int a = 0; a < 32; a += 16) {
            f16* G = P + 48 * U;
            conv_up_launch(D0, E3, W[7], B[7], G,         64, a,      16, 64, 64, s);
            conv_up_launch(D0, E3, W[7], B[7], G + 4 * U, 64, 32 + a, 16, 64, 64, s);
            pool_launch<true, f16, float, f16>(G, G + 4 * U, D1 + (size_t)a * V2,
                                               E2 + (size_t)a * V2, npf, 16, 16384, 0, s);
        }
    }
    // E2, E3, D0 dead.

    // ---- d2 = qrnn(deconv(d1), rev) : 32 -> 64 -> 32 @128 (MFMA, flip) -----
    // r14: 2 passes. z (co 0-31) -> D2 [8U,16U) (8U exact, over dead E2),
    // in-place pool; f (co 32-63) -> G [48U,56U).
    f16* D2 = P + 8 * U;
    if (packed) {
        f16* G = P + 48 * U;
        MFMA_CALL(1, true, 32, 128, 128, 2, D1, W[8], PK_d2, B[8], D2, 0, 32, 8);
        MFMA_CALL(1, true, 32, 128, 128, 2, D1, W[8], PK_d2, B[8], G, 32, 32, 8);
        pool_launch<true, f16, float, f16>(D2, G, D2, np, npf, 32, 16384, 1, s);
    } else {
        for (int a = 0; a < 32; a += 16) {
            f16* G = P + 48 * U;
            MFMA_CALL(1, true, 32, 128, 128, 1, D1, W[8], PK_d2, B[8], G,         a,      16, 8);
            MFMA_CALL(1, true, 32, 128, 128, 1, D1, W[8], PK_d2, B[8], G + 4 * U, 32 + a, 16, 8);
            pool_launch<true, f16, float, f16>(G, G + 4 * U, D2 + (size_t)a * V2, np, npf, 16, 16384, 1, s);
        }
    }
    // D1 dead.

    // ---- d3 = qrnn(conv(up(d2+e1)), fwd) + e0 : 32 -> 32 -> 16 @256 --------
    // S = D2+E1 in place. Dual calls: call1 co0-23 (z->D3 16U, f16-23->G 8U)
    // + in-place pool a=0; call2 co24-31 -> G + in-place pool a=8.
    f16* D3 = P + 32 * U;  // fresh 16U
    if (packed) {
        f16* G = P + 48 * U;
        add_launch(D2, E1, 8 * U, s);
        mfma_up_launch<32, 128, 128, 2>(D2, (const f16x8*)PK_d3, B[9], D3,
                                        G, 16, 0, 24, 4, s);
        pool_launch<true, f16, float, f16>(D3, G, D3, E0, npf, 8, 65536, 0, s);
        mfma_up_launch<32, 128, 128, 1>(D2, (const f16x8*)PK_d3, B[9], G,
                                        nullptr, COSPLIT_NONE, 24, 8, 4, s);
        pool_launch<true, f16, float, f16>(D3 + 8 * U, G, D3 + 8 * U,
                                           E0 + 8 * U, npf, 8, 65536, 0, s);
    } else {
        for (int a = 0; a < 16; a += 4) {
            f16* G = P + 48 * U;
            conv_up_launch(D2, E1, W[9], B[9], G,         32, a,      4, 128, 128, s);
            conv_up_launch(D2, E1, W[9], B[9], G + 4 * U, 32, 16 + a, 4, 128, 128, s);
            pool_launch<true, f16, float, f16>(G, G + 4 * U, D3 + (size_t)a * U,
                                               E0 + (size_t)a * U, npf, 4, 65536, 0, s);
        }
    }
    // E0, E1, D2 dead.

    // ---- fe again: reuse saved FE, or recompute into [0,16U) ---------------
    f16* FE2;
    if (saveFE) {
        FE2 = FE;  // still alive at [57U,73U)
    } else {
        FE2 = P;
        for (int a = 0; a < 16; a += 4) {
            f16* G = P + 16 * U;
            conv_fe_k<<<992, 256, 0, s>>>(x, W[0] + (size_t)a * 27,        B[0] + a,      G);
            conv_fe_k<<<992, 256, 0, s>>>(x, W[0] + (size_t)(16 + a) * 27, B[0] + 16 + a, G + 4 * U);
            conv_fe_k<<<992, 256, 0, s>>>(x, W[0] + (size_t)(32 + a) * 27, B[0] + 32 + a, G + 8 * U);
            pool_launch<true, f16, float, f16>(G, G + 4 * U, G + 12 * U, np, npf, 4, 65536, 0, s);
            pool_launch<true, f16, float, f16>(G, G + 8 * U, FE2 + (size_t)a * U, G + 12 * U, npf, 4, 65536, 1, s);
        }
    }

    // ---- d4 = qrnn(deconv(d3), rev) + fe : 16 -> 32 -> 16 @256 (dual) ------
    f16* D4 = P + 16 * U;
    if (packed) {
        f16* G = P + 48 * U;
        mfma_launch<1, true, 16, 256, 256, 2, true, true>(
            D3, W[10], (const f16x8*)PK_d4, B[10], D4, G, 16, 0, 24, 4, s);
        pool_launch<true, f16, float, f16>(D4, G, D4, FE2, npf, 8, 65536, 1, s);
        mfma_launch<1, true, 16, 256, 256, 1, true, true>(
            D3, W[10], (const f16x8*)PK_d4, B[10], G, nullptr, COSPLIT_NONE,
            24, 8, 4, s);
        pool_launch<true, f16, float, f16>(D4 + 8 * U, G, D4 + 8 * U,
                                           FE2 + 8 * U, npf, 8, 65536, 1, s);
    } else {
        for (int a = 0; a < 16; a += 4) {
            f16* G = P + 48 * U;
            conv_launch(D3, W[10], B[10], G,         16, a,      4, 256, 256, 256, 256, 1, true, s);
            conv_launch(D3, W[10], B[10], G + 4 * U, 16, 16 + a, 4, 256, 256, 256, 256, 1, true, s);
            pool_launch<true, f16, float, f16>(G, G + 4 * U, D4 + (size_t)a * U,
                                               FE2 + (size_t)a * U, npf, 4, 65536, 1, s);
        }
    }
    // D3, FE2 dead.

    // ---- out = biqrnn(deconv(d4)) + x : 16 -> 3 -> 1 @256 -> fp32 d_out ----
    {
        f16* G = P + 32 * U;   // plain: ch0 z, ch1 f1, ch2 f2 (3U, D3 dead)
        f16* TMP = P + 35 * U;
        if (packed) {
            mfma_launch<1, true, 16, 256, 256, 1, true, false>(
                D4, W[11], (const f16x8*)PK_rec, B[11], G, nullptr, COSPLIT_NONE,
                0, 3, 1, s);
        } else {
            conv_launch(D4, W[11], B[11], G, 16, 0, 3, 256, 256, 256, 256, 1, true, s);
        }
        pool_launch<false, f16, float, f16>(G, G + 1 * U, TMP, np, npf, 1, 65536, 0, s);
        pool_launch<false, f16, float, float>(G, G + 2 * U, out, TMP, x, 1, 65536, 1, s);
    }
#undef MFMA_CALL
}

extern "C" void kernel_launch(void* const* d_in, const int* in_sizes, int n_in,
                              void* d_out, int out_size, void* d_ws, size_t ws_size,
                              hipStream_t stream)
{
    const float* x = (const float*)d_in[0];
    const float* W[12];
    const float* B[12];
    for (int i = 0; i < 12; ++i) {
        W[i] = (const float*)d_in[1 + 2 * i];
        B[i] = (const float*)d_in[2 + 2 * i];
    }

    const size_t need_base = (size_t)(POOL_UNITS * U) * sizeof(f16);     // ~227 MB
    const size_t need_pack = (size_t)(57 * U) * sizeof(f16);             // +~4 MB
    const size_t need_save = (size_t)(74 * U) * sizeof(f16);             // +FE slot
    if (ws_size >= need_pack) {
        const bool saveFE = (ws_size >= need_save);
        run_net(x, W, B, (float*)d_out, (f16*)d_ws, true, saveFE, stream);
    } else if (ws_size >= need_base) {
        run_net(x, W, B, (float*)d_out, (f16*)d_ws, false, false, stream);
    } else {
        const float ws_mb = (float)((double)ws_size / 1048576.0);
        diag_k<<<(out_size + 255) / 256, 256, 0, stream>>>(
            (float*)d_out, ws_mb, out_size);
    }
}

// Round 15
// 3729.601 us; speedup vs baseline: 1.1534x; 1.0832x over previous
//
#include <hip/hip_runtime.h>
#include <hip/hip_bf16.h>
#include <cstdint>
#include <cstddef>

using f16 = _Float16;
typedef _Float16 f16x2 __attribute__((ext_vector_type(2)));
typedef _Float16 f16x8 __attribute__((ext_vector_type(8)));
typedef float f32x4 __attribute__((ext_vector_type(4)));

static constexpr int DD = 31;                      // depth (time) extent
static constexpr long long U  = 31LL * 256 * 256;  // 2,031,616 elems (1 ch @256)
static constexpr long long V2 = 31LL * 128 * 128;  //   507,904 (1 ch @128)
static constexpr long long POOL_UNITS = 56;        // pool = 56*U f16 elems (~227MB)
static constexpr int CP_CHUNK = 16;                // LDS weight chunk (ci pairs)
static constexpr int COSPLIT_NONE = 1 << 30;

union U32H2 { unsigned u; f16x2 h; };

__device__ __forceinline__ float toF(float v) { return v; }
__device__ __forceinline__ float toF(f16 v) { return (float)v; }
__device__ __forceinline__ void stv(float* p, float v) { *p = v; }
__device__ __forceinline__ void stv(f16* p, float v) { *p = (f16)v; }
__device__ __forceinline__ float sigm(float x) { return 1.f / (1.f + __expf(-x)); }

__device__ __forceinline__ unsigned packh2(float a, float b)
{
    U32H2 r; r.h = f16x2{(f16)a, (f16)b}; return r.u;
}
__device__ __forceinline__ unsigned addh2(unsigned a, unsigned b)
{
    U32H2 x, y, r; x.u = a; y.u = b; r.h = x.h + y.h; return r.u;
}
__device__ __forceinline__ float dot2f(unsigned v, unsigned w, float c)
{
#if __has_builtin(__builtin_amdgcn_fdot2)
    U32H2 uv, uw; uv.u = v; uw.u = w;
    return __builtin_amdgcn_fdot2(uv.h, uw.h, c, false);
#else
    U32H2 uv, uw; uv.u = v; uw.u = w;
    c = fmaf((float)uv.h.x, (float)uw.h.x, c);
    return fmaf((float)uv.h.y, (float)uw.h.y, c);
#endif
}

// ---------------------------------------------------------------------------
__global__ __launch_bounds__(256)
void fill_k(f16* p, long long n)
{
    const long long stride = (long long)gridDim.x * 256;
    for (long long i = (long long)blockIdx.x * 256 + threadIdx.x; i < n; i += stride)
        p[i] = (f16)0.f;
}

// a += b elementwise (f16, 8-wide). Pre-sums skip inputs so the up-conv
// stages ONE tensor (r12: FETCH 382->95MB). Bitwise-identical f16 adds.
__global__ __launch_bounds__(256)
void add_k(f16* __restrict__ a, const f16* __restrict__ b, long long n8)
{
    const long long i = (long long)blockIdx.x * 256 + threadIdx.x;
    if (i >= n8) return;
    uint4 va = ((const uint4*)a)[i];
    const uint4 vb = ((const uint4*)b)[i];
    va.x = addh2(va.x, vb.x); va.y = addh2(va.y, vb.y);
    va.z = addh2(va.z, vb.z); va.w = addh2(va.w, vb.w);
    ((uint4*)a)[i] = va;
}

// ---------------------------------------------------------------------------
// Weight prepack: fp32 [nCo][CIN][27] -> f16x8 MFMA B-fragments, FLIP folded.
// Entry e = ((cc*nhg + hg)*9 + kd*3+Tg)*64 + lane; lane l holds co hg*8+(l&15)
// tap T=Tg*4+(l>>4), elems = 8 ci of chunk cc. nhg = ceil(nCo/8).
// ---------------------------------------------------------------------------
__global__ __launch_bounds__(256)
void pack_w_k(const float* __restrict__ wt, f16* __restrict__ outp,
              int CIN, int nCo, int flip)
{
    const int e = blockIdx.x * 256 + threadIdx.x;
    const int nhg = (nCo + 7) >> 3;
    const int total = (CIN >> 3) * nhg * 9 * 64;
    if (e >= total) return;
    const int l = e & 63;
    const int r = e >> 6;
    const int r9 = r % 9;
    const int t2 = r / 9;
    const int hg = t2 % nhg;
    const int cc = t2 / nhg;
    const int kd = r9 / 3, Tg = r9 - kd * 3;
    const int n = hg * 8 + (l & 15);
    const int T = Tg * 4 + (l >> 4);
    f16x8 bv;
#pragma unroll
    for (int i = 0; i < 8; ++i) bv[i] = (f16)0.f;
    if (T <= 8 && n < nCo) {
        const int kh = T / 3, kw = T - (T / 3) * 3;
        const int st = flip ? ((2 - kd) * 9 + (2 - kh) * 3 + (2 - kw))
                            : (kd * 9 + kh * 3 + kw);
        const size_t wb8 = ((size_t)n * CIN + cc * 8) * 27 + st;
#pragma unroll
        for (int i = 0; i < 8; ++i)
            bv[i] = (f16)wt[wb8 + (size_t)i * 27];
    }
    *(f16x8*)(outp + (size_t)e * 8) = bv;
}

// ---------------------------------------------------------------------------
// MFMA implicit-GEMM conv3d, 3x3x3, pad 1, pair-interleaved in [C/2][D][H][W][2]
// f16. v_mfma_f32_16x16x32_f16. Packed-B register loads issued before the A
// barrier (r9-proven). Tri-output (r15): rel co < coSplit -> out, < coSplit2
// -> outF at co-coSplit, else outF2 at co-coSplit2 (all IL). Lets one halo
// pass produce z AND split-f gates. OUTIL=false -> plain store (rec).
// Fragment layouts: A row=lane&15, k=(lane>>4)*8+e; B col=lane&15, same k;
// D col=lane&15, row=(lane>>4)*4+reg [m89/m91].
// ---------------------------------------------------------------------------
template<int STRIDE, bool FLIP, int CIN, int HOUT, int WOUT, int NT, bool PACKED,
         bool OUTIL>
__global__ __launch_bounds__(256)
void conv_mfma_k(const f16* __restrict__ in, const float* __restrict__ wt,
                 const f16x8* __restrict__ wb, const float* __restrict__ bias,
                 f16* __restrict__ out, f16* __restrict__ outF,
                 f16* __restrict__ outF2, int coSplit, int coSplit2,
                 int nCo, int cg0, int nhg)
{
    constexpr int CIC = CIN / 8;
    constexpr int HIN = HOUT * STRIDE, WIN = WOUT * STRIDE;
    constexpr int WT = (WOUT > 128) ? 128 : WOUT;   // 128 or 64
    constexpr int RR = 128 / WT;                    // rows per block
    constexpr int COLS = WOUT / WT;
    constexpr int TPD = (HOUT / RR) * COLS;
    constexpr int AH = STRIDE * (RR - 1) + 3;
    constexpr int AW = STRIDE * (WT - 1) + 3;
    constexpr int APOS = 3 * AH * AW;
    constexpr int NBENT = NT * 576;                 // B entries (fallback)

    extern __shared__ unsigned lds[];
    unsigned* Alds = lds;                           // APOS*4 dwords
    unsigned* Blds = lds + APOS * 4;                // fallback only

    const int tid = threadIdx.x;
    const int l = tid & 63;
    const int wid = tid >> 6;

    const int bx = blockIdx.x;
    const int d0 = bx / TPD;
    const int rem = bx - d0 * TPD;
    const int h0 = (rem / COLS) * RR;
    const int wb_ = (rem % COLS) * WT;

    const int co_base = blockIdx.y * (16 * NT);
    const int nRem = nCo - co_base;
    const int hgBase = cg0 + blockIdx.y * (2 * NT);

    const int base_h = STRIDE * h0 - 1;
    const int base_w = STRIDE * wb_ - 1;
    constexpr size_t HWin = (size_t)HIN * WIN;
    constexpr size_t DHW = (size_t)DD * HWin;       // dwords per channel-pair
    const unsigned* inu = (const unsigned*)in;

    // spatial decode for this lane's two A m-tiles
    int hho[2], wlo[2];
#pragma unroll
    for (int mt = 0; mt < 2; ++mt) {
        const int p = wid * 32 + mt * 16 + (l & 15);
        hho[mt] = p / WT;
        wlo[mt] = p - hho[mt] * WT;
    }
    // lane's tap slot per tap-group
    const int g = l >> 4;
    int khg[3], kwg[3];
#pragma unroll
    for (int Tg = 0; Tg < 3; ++Tg) {
        int T = Tg * 4 + g;
        if (T > 8) T = 8;                           // clamped; B is zero there
        khg[Tg] = T / 3;
        kwg[Tg] = T - (T / 3) * 3;
    }

    f32x4 acc[2][NT];
#pragma unroll
    for (int mt = 0; mt < 2; ++mt)
#pragma unroll
        for (int nt = 0; nt < NT; ++nt)
            acc[mt][nt] = (f32x4){0.f, 0.f, 0.f, 0.f};

    for (int cc = 0; cc < CIC; ++cc) {
        // ---- PACKED: issue B register loads early (latency hides under A) -
        f16x8 bfr[NT][9];
        if (PACKED) {
#pragma unroll
            for (int nt = 0; nt < NT; ++nt)
#pragma unroll
                for (int r9 = 0; r9 < 9; ++r9)
                    bfr[nt][r9] = wb[((size_t)cc * nhg + hgBase + nt * 2) * 9 * 64
                                     + (size_t)r9 * 64 + l];
        }
        __syncthreads();
        // ---- stage A chunk: 4 cp (8 ci) per position ----------------------
        for (int t = tid; t < APOS; t += 256) {
            const int ww = t % AW;
            const int t2 = t / AW;
            const int hh = t2 % AH;
            const int dd = t2 / AH;
            const int d = d0 - 1 + dd;
            const int h = base_h + hh;
            const int w = base_w + ww;
            uint4 val = make_uint4(0u, 0u, 0u, 0u);
            if ((unsigned)d < (unsigned)DD && (unsigned)h < (unsigned)HIN &&
                (unsigned)w < (unsigned)WIN) {
                const size_t gi = (size_t)(cc * 4) * DHW +
                                  (size_t)d * HWin + (size_t)h * WIN + w;
                val.x = inu[gi];
                val.y = inu[gi + DHW];
                val.z = inu[gi + 2 * DHW];
                val.w = inu[gi + 3 * DHW];
            }
            *(uint4*)(Alds + (size_t)t * 4) = val;
        }
        // ---- fallback: stage B fragments via fp32 gather ------------------
        if (!PACKED) {
            for (int t = tid; t < NBENT; t += 256) {
                const int ll = t & 63;
                const int f = t >> 6;
                const int nt = f / 9;
                const int r9 = f - nt * 9;
                const int kd = r9 / 3;
                const int Tg = r9 - kd * 3;
                const int n = nt * 16 + (ll & 15);
                const int gg = ll >> 4;
                const int T = Tg * 4 + gg;
                f16x8 bv;
                if (T <= 8 && n < nRem) {
                    const int kh = T / 3, kw = T - (T / 3) * 3;
                    const int st = FLIP ? ((2 - kd) * 9 + (2 - kh) * 3 + (2 - kw))
                                        : (kd * 9 + kh * 3 + kw);
                    const size_t wb8 = ((size_t)(co_base + n) * CIN + cc * 8) * 27 + st;
#pragma unroll
                    for (int e = 0; e < 8; ++e)
                        bv[e] = (f16)wt[wb8 + (size_t)e * 27];
                } else {
#pragma unroll
                    for (int e = 0; e < 8; ++e) bv[e] = (f16)0.f;
                }
                *(f16x8*)(Blds + (size_t)t * 4) = bv;
            }
        }
        __syncthreads();
        // ---- compute: 3 kd x 3 tap-groups x 2 m-tiles x NT n-tiles --------
#pragma unroll
        for (int kd = 0; kd < 3; ++kd) {
#pragma unroll
            for (int Tg = 0; Tg < 3; ++Tg) {
                f16x8 bfrag[NT];
#pragma unroll
                for (int nt = 0; nt < NT; ++nt)
                    bfrag[nt] = PACKED ? bfr[nt][kd * 3 + Tg]
                                       : *(const f16x8*)
                        (Blds + (size_t)(((nt * 9) + kd * 3 + Tg) * 64 + l) * 4);
                const int kh = khg[Tg], kw = kwg[Tg];
#pragma unroll
                for (int mt = 0; mt < 2; ++mt) {
                    const int hh = STRIDE * hho[mt] + kh;
                    const int ww = STRIDE * wlo[mt] + kw;
                    const f16x8 afrag = *(const f16x8*)
                        (Alds + (size_t)((kd * AH + hh) * AW + ww) * 4);
#pragma unroll
                    for (int nt = 0; nt < NT; ++nt)
                        acc[mt][nt] = __builtin_amdgcn_mfma_f32_16x16x32_f16(
                            afrag, bfrag[nt], acc[mt][nt], 0, 0, 0);
                }
            }
        }
    }

    // ---- store: D lane mapping col(n)=lane&15, row m=(lane>>4)*4+r --------
    const int n = l & 15;
#pragma unroll
    for (int nt = 0; nt < NT; ++nt) {
        const int ng = nt * 16 + n;
        if (ng < nRem) {
            const int co = co_base + ng;
            const float bv = bias[co];
            f16* dst = out;
            int cs = co;
            if (OUTIL && co >= coSplit2) { dst = outF2; cs = co - coSplit2; }
            else if (OUTIL && co >= coSplit) { dst = outF; cs = co - coSplit; }
#pragma unroll
            for (int mt = 0; mt < 2; ++mt) {
#pragma unroll
                for (int r = 0; r < 4; ++r) {
                    const int p = wid * 32 + mt * 16 + (l >> 4) * 4 + r;
                    const int hh = p / WT;
                    const int wl = p - hh * WT;
                    const int h = h0 + hh, w = wb_ + wl;
                    const float val = acc[mt][nt][r] + bv;
                    if (OUTIL) {
                        const size_t coPlane =
                            (size_t)(cs >> 1) * DD * HOUT * WOUT * 2 + (cs & 1);
                        dst[coPlane + ((size_t)d0 * HOUT + h) * WOUT * 2 +
                            (size_t)w * 2] = (f16)val;
                    } else {
                        out[((size_t)co * DD + d0) * HOUT * WOUT +
                            (size_t)h * WOUT + w] = (f16)val;
                    }
                }
            }
        }
    }
}

// ---------------------------------------------------------------------------
// MFMA fused conv3d( upsample2x(S) ), stride 1, no flip, IL; S pre-summed.
// r12 staging (measured best): lo-res halo, padded row stride AWLOP,
// pair-collapsed read iw = ((wpos+kw-1)>>1)+1. Cross-tap-group bank aliasing
// is STRUCTURAL to the per-group tap mapping (r13/r14 analysis) -- parked.
// RR=1. Tri-output like conv_mfma_k.
// ---------------------------------------------------------------------------
template<int CIN, int HLO, int WLO, int NT>
__global__ __launch_bounds__(256)
void conv_mfma_up_k(const f16* __restrict__ in, const f16x8* __restrict__ wb,
                    const float* __restrict__ bias, f16* __restrict__ out,
                    f16* __restrict__ outF, f16* __restrict__ outF2,
                    int coSplit, int coSplit2, int nCo, int cg0, int nhg)
{
    constexpr int CIC = CIN / 8;
    constexpr int HOUT = 2 * HLO, WOUT = 2 * WLO;
    constexpr int WT = (WOUT > 128) ? 128 : WOUT;
    constexpr int COLS = WOUT / WT;
    constexpr int TPD = HOUT * COLS;                // RR = 1
    constexpr int AWLO = WT / 2 + 2;
    constexpr int AWLOP = AWLO + 1;                 // padded row stride
    constexpr int APOS = 3 * 2 * AWLO;              // staged entries

    extern __shared__ unsigned lds[];               // 3*2*AWLOP uint4

    const int tid = threadIdx.x;
    const int l = tid & 63;
    const int wid = tid >> 6;

    const int bx = blockIdx.x;
    const int d0 = bx / TPD;
    const int rem = bx - d0 * TPD;
    const int h0 = rem / COLS;
    const int wb_ = (rem % COLS) * WT;

    const int co_base = blockIdx.y * (16 * NT);
    const int nRem = nCo - co_base;
    const int hgBase = cg0 + blockIdx.y * (2 * NT);

    const int rlo0 = (h0 - 1) >> 1;                 // arithmetic shift
    const int clo0 = (wb_ >> 1) - 1;

    constexpr size_t HWlo = (size_t)HLO * WLO;
    constexpr size_t DHW = (size_t)DD * HWlo;
    const unsigned* inu = (const unsigned*)in;

    int wpos[2];
#pragma unroll
    for (int mt = 0; mt < 2; ++mt)
        wpos[mt] = wid * 32 + mt * 16 + (l & 15);

    const int g = l >> 4;
    int khg[3], kwg[3];
#pragma unroll
    for (int Tg = 0; Tg < 3; ++Tg) {
        int T = Tg * 4 + g;
        if (T > 8) T = 8;
        khg[Tg] = T / 3;
        kwg[Tg] = T - (T / 3) * 3;
    }

    f32x4 acc[2][NT];
#pragma unroll
    for (int mt = 0; mt < 2; ++mt)
#pragma unroll
        for (int nt = 0; nt < NT; ++nt)
            acc[mt][nt] = (f32x4){0.f, 0.f, 0.f, 0.f};

    for (int cc = 0; cc < CIC; ++cc) {
        f16x8 bfr[NT][9];
#pragma unroll
        for (int nt = 0; nt < NT; ++nt)
#pragma unroll
            for (int r9 = 0; r9 < 9; ++r9)
                bfr[nt][r9] = wb[((size_t)cc * nhg + hgBase + nt * 2) * 9 * 64
                                 + (size_t)r9 * 64 + l];
        __syncthreads();
        for (int t = tid; t < APOS; t += 256) {
            const int ww = t % AWLO;
            const int t2 = t / AWLO;
            const int rr = t2 & 1;
            const int dd = t2 >> 1;
            const int d = d0 - 1 + dd;
            const int hlo = rlo0 + rr;
            const int wlo = clo0 + ww;
            uint4 val = make_uint4(0u, 0u, 0u, 0u);
            if ((unsigned)d < (unsigned)DD && (unsigned)hlo < (unsigned)HLO &&
                (unsigned)wlo < (unsigned)WLO) {
                const size_t gi = (size_t)(cc * 4) * DHW +
                                  (size_t)d * HWlo + (size_t)hlo * WLO + wlo;
                val.x = inu[gi];
                val.y = inu[gi + DHW];
                val.z = inu[gi + 2 * DHW];
                val.w = inu[gi + 3 * DHW];
            }
            *(uint4*)(lds + (size_t)((dd * 2 + rr) * AWLOP + ww) * 4) = val;
        }
        __syncthreads();
#pragma unroll
        for (int kd = 0; kd < 3; ++kd) {
#pragma unroll
            for (int Tg = 0; Tg < 3; ++Tg) {
                const int kh = khg[Tg], kw = kwg[Tg];
                const int rr = ((h0 + kh - 1) >> 1) - rlo0;   // 0 or 1
#pragma unroll
                for (int mt = 0; mt < 2; ++mt) {
                    const int iw = ((wpos[mt] + kw - 1) >> 1) + 1;
                    const f16x8 afrag = *(const f16x8*)
                        (lds + (size_t)((kd * 2 + rr) * AWLOP + iw) * 4);
#pragma unroll
                    for (int nt = 0; nt < NT; ++nt)
                        acc[mt][nt] = __builtin_amdgcn_mfma_f32_16x16x32_f16(
                            afrag, bfr[nt][kd * 3 + Tg], acc[mt][nt], 0, 0, 0);
                }
            }
        }
    }

    const int n = l & 15;
#pragma unroll
    for (int nt = 0; nt < NT; ++nt) {
        const int ng = nt * 16 + n;
        if (ng < nRem) {
            const int co = co_base + ng;
            const float bv = bias[co];
            f16* dst = out;
            int cs = co;
            if (co >= coSplit2) { dst = outF2; cs = co - coSplit2; }
            else if (co >= coSplit) { dst = outF; cs = co - coSplit; }
            const size_t coPlane = (size_t)(cs >> 1) * DD * HOUT * WOUT * 2 + (cs & 1);
#pragma unroll
            for (int mt = 0; mt < 2; ++mt) {
#pragma unroll
                for (int r = 0; r < 4; ++r) {
                    const int p = wid * 32 + mt * 16 + (l >> 4) * 4 + r;
                    dst[coPlane + ((size_t)d0 * HOUT + h0) * WOUT * 2 +
                        (size_t)(wb_ + p) * 2] = (f16)(acc[mt][nt][r] + bv);
                }
            }
        }
    }
}

// ---------------------------------------------------------------------------
// Scalar pair-interleaved direct conv3d (fallback only). W-tile 8, dot2.
// ---------------------------------------------------------------------------
template<int STRIDE, bool FLIP, int CO_BLK, bool OUT_IL>
__global__ __launch_bounds__(256, 2)
void conv3d_il_k(const f16* __restrict__ in, const float* __restrict__ wt,
                 const float* __restrict__ bias, f16* __restrict__ out,
                 int Cin, int Hin, int Win, int Hout, int Wout)
{
    extern __shared__ unsigned wl2[];  // [CP_CHUNK*27][CO_BLK]
    const int co_base = blockIdx.y * CO_BLK;

    const int s8 = (blockIdx.x * 256 + threadIdx.x) * 8;
    const int w0 = s8 % Wout;
    const int sh = s8 / Wout;
    const int h0 = sh % Hout;
    const int d0 = sh / Hout;

    float acc[CO_BLK][8];
#pragma unroll
    for (int j = 0; j < CO_BLK; ++j) {
        const float bv = bias[co_base + j];
#pragma unroll
        for (int o = 0; o < 8; ++o) acc[j][o] = bv;
    }

    const size_t HWin = (size_t)Hin * Win;
    const int CP = Cin >> 1;

    for (int cp0 = 0; cp0 < CP; cp0 += CP_CHUNK) {
        const int cnp = (CP - cp0 < CP_CHUNK) ? (CP - cp0) : CP_CHUNK;
        __syncthreads();
        for (int t = threadIdx.x; t < cnp * 27 * CO_BLK; t += 256) {
            const int j = t % CO_BLK;
            const int k = (t / CO_BLK) % 27;
            const int cp = t / (CO_BLK * 27);
            int src;
            if (FLIP) {
                const int kd = k / 9, kh = (k / 3) % 3, kw = k % 3;
                src = (2 - kd) * 9 + (2 - kh) * 3 + (2 - kw);
            } else {
                src = k;
            }
            const int ci = (cp0 + cp) * 2;
            const size_t wb = (size_t)(co_base + j) * Cin;
            wl2[t] = packh2(wt[(wb + ci) * 27 + src], wt[(wb + ci + 1) * 27 + src]);
        }
        __syncthreads();

        for (int cp = 0; cp < cnp; ++cp) {
            const f16* cb = in + (size_t)(cp0 + cp) * DD * HWin * 2;
            const unsigned* wc = wl2 + cp * 27 * CO_BLK;
#pragma unroll
            for (int kd = 0; kd < 3; ++kd) {
                const int di = d0 + kd - 1;
                if (di < 0 || di >= DD) continue;
#pragma unroll
                for (int kh = 0; kh < 3; ++kh) {
                    const int hi = h0 * STRIDE + kh - 1;
                    if (hi < 0 || hi >= Hin) continue;
                    const unsigned* rowu = (const unsigned*)
                        (cb + ((size_t)di * HWin + (size_t)hi * Win) * 2);
                    if (STRIDE == 1) {
                        unsigned v2[10];
                        v2[0] = (w0 > 0) ? rowu[w0 - 1] : 0u;
                        const uint4 q1 = *(const uint4*)(rowu + w0);
                        const uint4 q2 = *(const uint4*)(rowu + w0 + 4);
                        v2[1] = q1.x; v2[2] = q1.y; v2[3] = q1.z; v2[4] = q1.w;
                        v2[5] = q2.x; v2[6] = q2.y; v2[7] = q2.z; v2[8] = q2.w;
                        v2[9] = (w0 + 8 < Win) ? rowu[w0 + 8] : 0u;
                        const unsigned* wk = wc + (kd * 9 + kh * 3) * CO_BLK;
#pragma unroll
                        for (int kw = 0; kw < 3; ++kw) {
#pragma unroll
                            for (int j = 0; j < CO_BLK; ++j) {
                                const unsigned wv = wk[kw * CO_BLK + j];
#pragma unroll
                                for (int o = 0; o < 8; ++o)
                                    acc[j][o] = dot2f(v2[o + kw], wv, acc[j][o]);
                            }
                        }
                    } else {
                        unsigned v2[17];
                        const int p0 = w0 * 2;
                        v2[0] = (w0 > 0) ? rowu[p0 - 1] : 0u;
#pragma unroll
                        for (int q = 0; q < 4; ++q) {
                            const uint4 qq = *(const uint4*)(rowu + p0 + 4 * q);
                            v2[1 + 4 * q] = qq.x; v2[2 + 4 * q] = qq.y;
                            v2[3 + 4 * q] = qq.z; v2[4 + 4 * q] = qq.w;
                        }
                        const unsigned* wk = wc + (kd * 9 + kh * 3) * CO_BLK;
#pragma unroll
                        for (int kw = 0; kw < 3; ++kw) {
#pragma unroll
                            for (int j = 0; j < CO_BLK; ++j) {
                                const unsigned wv = wk[kw * CO_BLK + j];
#pragma unroll
                                for (int o = 0; o < 8; ++o)
                                    acc[j][o] = dot2f(v2[2 * o + kw], wv, acc[j][o]);
                            }
                        }
                    }
                }
            }
        }
    }

    if (OUT_IL) {
#pragma unroll
        for (int pj = 0; pj < CO_BLK / 2; ++pj) {
            f16* op = out + ((((size_t)((co_base >> 1) + pj) * DD + d0) * Hout + h0)
                             * Wout + w0) * 2;
            unsigned dw[8];
#pragma unroll
            for (int o = 0; o < 8; ++o)
                dw[o] = packh2(acc[2 * pj][o], acc[2 * pj + 1][o]);
            *(uint4*)op = make_uint4(dw[0], dw[1], dw[2], dw[3]);
            *(uint4*)(op + 8) = make_uint4(dw[4], dw[5], dw[6], dw[7]);
        }
    } else {
#pragma unroll
        for (int j = 0; j < CO_BLK; ++j) {
            f16* op = out + (((size_t)(co_base + j) * DD + d0) * Hout + h0) * Wout + w0;
            unsigned dw[4];
#pragma unroll
            for (int o = 0; o < 4; ++o)
                dw[o] = packh2(acc[j][2 * o], acc[j][2 * o + 1]);
            *(uint4*)op = make_uint4(dw[0], dw[1], dw[2], dw[3]);
        }
    }
}

// ---------------------------------------------------------------------------
// Scalar fused conv3d( upsample2x(a + b) ) (fallback only).
// ---------------------------------------------------------------------------
template<int CO_BLK>
__global__ __launch_bounds__(256, 2)
void conv3d_up_il_k(const f16* __restrict__ ia, const f16* __restrict__ ib,
                    const float* __restrict__ wt, const float* __restrict__ bias,
                    f16* __restrict__ out, int Cin, int Hlo, int Wlo)
{
    extern __shared__ unsigned wl2[];
    const int co_base = blockIdx.y * CO_BLK;

    const int Hout = 2 * Hlo, Wout = 2 * Wlo;
    const int s8 = (blockIdx.x * 256 + threadIdx.x) * 8;
    const int w0 = s8 % Wout;
    const int sh = s8 / Wout;
    const int h0 = sh % Hout;
    const int d0 = sh / Hout;
    const int lw = w0 >> 1;  // multiple of 4

    float acc[CO_BLK][8];
#pragma unroll
    for (int j = 0; j < CO_BLK; ++j) {
        const float bv = bias[co_base + j];
#pragma unroll
        for (int o = 0; o < 8; ++o) acc[j][o] = bv;
    }
    const size_t HWlo = (size_t)Hlo * Wlo;
    const int CP = Cin >> 1;

    for (int cp0 = 0; cp0 < CP; cp0 += CP_CHUNK) {
        const int cnp = (CP - cp0 < CP_CHUNK) ? (CP - cp0) : CP_CHUNK;
        __syncthreads();
        for (int t = threadIdx.x; t < cnp * 27 * CO_BLK; t += 256) {
            const int j = t % CO_BLK;
            const int k = (t / CO_BLK) % 27;
            const int cp = t / (CO_BLK * 27);
            const int ci = (cp0 + cp) * 2;
            const size_t wb = (size_t)(co_base + j) * Cin;
            wl2[t] = packh2(wt[(wb + ci) * 27 + k], wt[(wb + ci + 1) * 27 + k]);
        }
        __syncthreads();

        for (int cp = 0; cp < cnp; ++cp) {
            const f16* cba = ia + (size_t)(cp0 + cp) * DD * HWlo * 2;
            const f16* cbb = ib + (size_t)(cp0 + cp) * DD * HWlo * 2;
            const unsigned* wc = wl2 + cp * 27 * CO_BLK;
#pragma unroll
            for (int kd = 0; kd < 3; ++kd) {
                const int di = d0 + kd - 1;
                if (di < 0 || di >= DD) continue;
#pragma unroll
                for (int kh = 0; kh < 3; ++kh) {
                    const int hi = h0 + kh - 1;
                    if (hi < 0 || hi >= Hout) continue;
                    const int hlo = hi >> 1;
                    const unsigned* rua = (const unsigned*)
                        (cba + ((size_t)di * HWlo + (size_t)hlo * Wlo) * 2);
                    const unsigned* rub = (const unsigned*)
                        (cbb + ((size_t)di * HWlo + (size_t)hlo * Wlo) * 2);
                    unsigned u[6];
                    u[0] = (lw > 0) ? addh2(rua[lw - 1], rub[lw - 1]) : 0u;
                    const uint4 qa = *(const uint4*)(rua + lw);
                    const uint4 qb = *(const uint4*)(rub + lw);
                    u[1] = addh2(qa.x, qb.x); u[2] = addh2(qa.y, qb.y);
                    u[3] = addh2(qa.z, qb.z); u[4] = addh2(qa.w, qb.w);
                    u[5] = (lw + 4 < Wlo) ? addh2(rua[lw + 4], rub[lw + 4]) : 0u;
                    // upsampled window: up-w = w0-1+t, t in [0,10)
                    const unsigned v2[10] = { u[0], u[1], u[1], u[2], u[2],
                                              u[3], u[3], u[4], u[4], u[5] };
                    const unsigned* wk = wc + (kd * 9 + kh * 3) * CO_BLK;
#pragma unroll
                    for (int kw = 0; kw < 3; ++kw) {
#pragma unroll
                        for (int j = 0; j < CO_BLK; ++j) {
                            const unsigned wv = wk[kw * CO_BLK + j];
#pragma unroll
                            for (int o = 0; o < 8; ++o)
                                acc[j][o] = dot2f(v2[o + kw], wv, acc[j][o]);
                        }
                    }
                }
            }
        }
    }
#pragma unroll
    for (int pj = 0; pj < CO_BLK / 2; ++pj) {
        f16* op = out + ((((size_t)((co_base >> 1) + pj) * DD + d0) * Hout + h0)
                         * Wout + w0) * 2;
        unsigned dw[8];
#pragma unroll
        for (int o = 0; o < 8; ++o)
            dw[o] = packh2(acc[2 * pj][o], acc[2 * pj + 1][o]);
        *(uint4*)op = make_uint4(dw[0], dw[1], dw[2], dw[3]);
        *(uint4*)(op + 8) = make_uint4(dw[4], dw[5], dw[6], dw[7]);
    }
}

// ---------------------------------------------------------------------------
// fe conv: Cin=1, fp32 plain input x, interleaved f16 out (CO_BLK=4). @256^2.
// ---------------------------------------------------------------------------
__global__ __launch_bounds__(256, 2)
void conv_fe_k(const float* __restrict__ in, const float* __restrict__ wt,
               const float* __restrict__ bias, f16* __restrict__ out)
{
    __shared__ float wl[27 * 4];
    for (int t = threadIdx.x; t < 27 * 4; t += 256) {
        const int j = t % 4;
        const int k = t / 4;
        wl[t] = wt[(size_t)j * 27 + k];
    }
    __syncthreads();

    const int W = 256, H = 256;
    const int s8 = (blockIdx.x * 256 + threadIdx.x) * 8;
    const int w0 = s8 % W;
    const int sh = s8 / W;
    const int h0 = sh % H;
    const int d0 = sh / H;

    float acc[4][8];
#pragma unroll
    for (int j = 0; j < 4; ++j) {
        const float bv = bias[j];
#pragma unroll
        for (int o = 0; o < 8; ++o) acc[j][o] = bv;
    }
    const size_t HW = 65536;

#pragma unroll
    for (int kd = 0; kd < 3; ++kd) {
        const int di = d0 + kd - 1;
        if (di < 0 || di >= DD) continue;
#pragma unroll
        for (int kh = 0; kh < 3; ++kh) {
            const int hi = h0 + kh - 1;
            if (hi < 0 || hi >= H) continue;
            const float* row = in + (size_t)di * HW + (size_t)hi * W + w0;
            float v[10];
            v[0] = (w0 > 0) ? row[-1] : 0.f;
            const float4 q1 = *(const float4*)row;
            const float4 q2 = *(const float4*)(row + 4);
            v[1] = q1.x; v[2] = q1.y; v[3] = q1.z; v[4] = q1.w;
            v[5] = q2.x; v[6] = q2.y; v[7] = q2.z; v[8] = q2.w;
            v[9] = (w0 + 8 < W) ? row[8] : 0.f;
            const float* wk = wl + (kd * 9 + kh * 3) * 4;
#pragma unroll
            for (int kw = 0; kw < 3; ++kw) {
#pragma unroll
                for (int j = 0; j < 4; ++j) {
                    const float wv = wk[kw * 4 + j];
#pragma unroll
                    for (int o = 0; o < 8; ++o)
                        acc[j][o] = fmaf(v[o + kw], wv, acc[j][o]);
                }
            }
        }
    }
#pragma unroll
    for (int pj = 0; pj < 2; ++pj) {
        f16* op = out + (((size_t)pj * DD + d0) * H + h0) * (size_t)W * 2 + (size_t)w0 * 2;
        unsigned dw[8];
#pragma unroll
        for (int o = 0; o < 8; ++o)
            dw[o] = packh2(acc[2 * pj][o], acc[2 * pj + 1][o]);
        *(uint4*)op = make_uint4(dw[0], dw[1], dw[2], dw[3]);
        *(uint4*)(op + 8) = make_uint4(dw[4], dw[5], dw[6], dw[7]);
    }
}

// ---------------------------------------------------------------------------
// fo_pool over D=31. IL=true: pair-interleaved [C/2][D][HW][2]; else plain
// [C][D][HW]. out = h_d + a1? + a2?  In-place (out==z or out==f) is safe:
// each element is read (z then f) before the same thread overwrites it.
// ---------------------------------------------------------------------------
template<bool IL, typename TA1, typename TA2, typename TO>
__global__ __launch_bounds__(256)
void fo_pool_k(const f16* __restrict__ z, const f16* __restrict__ f,
               TO* __restrict__ out, const TA1* __restrict__ a1,
               const TA2* __restrict__ a2, int C, int HW, int reverse)
{
    const long long idx = (long long)blockIdx.x * 256 + threadIdx.x;
    if (idx >= (long long)C * HW) return;
    size_t base; size_t step;
    if (IL) {
        const long long pairIdx = idx / (2LL * HW);
        const int rem = (int)(idx - pairIdx * 2LL * HW);
        const int p = rem >> 1;
        const int par = rem & 1;
        base = ((size_t)pairIdx * DD * HW + p) * 2 + par;
        step = (size_t)HW * 2;
    } else {
        const int c = (int)(idx / HW);
        const int p = (int)(idx - (long long)c * HW);
        base = (size_t)c * DD * HW + p;
        step = (size_t)HW;
    }
    float h = 0.f;
    if (!reverse) {
        for (int d = 0; d < DD; ++d) {
            const size_t off = base + (size_t)d * step;
            const float zz = tanhf(toF(z[off]));
            const float ff = sigm(toF(f[off]));
            h = ff * h + (1.f - ff) * zz;
            float v = h;
            if (a1) v += toF(a1[off]);
            if (a2) v += toF(a2[off]);
            stv(out + off, v);
        }
    } else {
        for (int d = DD - 1; d >= 0; --d) {
            const size_t off = base + (size_t)d * step;
            const float zz = tanhf(toF(z[off]));
            const float ff = sigm(toF(f[off]));
            h = ff * h + (1.f - ff) * zz;
            float v = h;
            if (a1) v += toF(a1[off]);
            if (a2) v += toF(a2[off]);
            stv(out + off, v);
        }
    }
}

// Diagnostic: encode ws_size (MB) into output if workspace too small.
__global__ __launch_bounds__(256)
void diag_k(float* out, float v, int n)
{
    const int i = blockIdx.x * 256 + threadIdx.x;
    if (i < n) out[i] = v;
}

// ---------------------------------------------------------------------------

template<int STRIDE, bool FLIP, int CIN, int HOUT, int WOUT, int NT, bool PACKED,
         bool OUTIL>
static inline void mfma_launch(const f16* in, const float* w, const f16x8* wb,
                               const float* b, f16* out, f16* outF, f16* outF2,
                               int coSplit, int coSplit2,
                               int co0, int nCo, int nhg, hipStream_t s)
{
    constexpr int WT = WOUT > 128 ? 128 : WOUT;
    constexpr int RR = 128 / WT;
    constexpr int AH = STRIDE * (RR - 1) + 3;
    constexpr int AW = STRIDE * (WT - 1) + 3;
    constexpr size_t lds = (size_t)(3 * AH * AW) * 16 +
                           (PACKED ? 0 : (size_t)NT * 9216);
    dim3 grid((unsigned)(DD * (HOUT / RR) * (WOUT / WT)),
              (unsigned)((nCo + 16 * NT - 1) / (16 * NT)));
    conv_mfma_k<STRIDE, FLIP, CIN, HOUT, WOUT, NT, PACKED, OUTIL>
        <<<grid, 256, lds, s>>>(
        in, w + (size_t)co0 * CIN * 27, wb, b + co0, out, outF, outF2,
        coSplit, coSplit2, nCo, co0 / 8, nhg);
}

template<int CIN, int HLO, int WLO, int NT>
static inline void mfma_up_launch(const f16* in, const f16x8* wb,
                                  const float* b, f16* out, f16* outF,
                                  f16* outF2, int coSplit, int coSplit2,
                                  int co0, int nCo, int nhg, hipStream_t s)
{
    constexpr int WOUT = 2 * WLO;
    constexpr int WT = WOUT > 128 ? 128 : WOUT;
    constexpr int AWLOP = WT / 2 + 3;
    constexpr size_t lds = (size_t)(3 * 2 * AWLOP) * 16;
    dim3 grid((unsigned)(DD * (2 * HLO) * (WOUT / WT)),
              (unsigned)((nCo + 16 * NT - 1) / (16 * NT)));
    conv_mfma_up_k<CIN, HLO, WLO, NT><<<grid, 256, lds, s>>>(
        in, wb, b + co0, out, outF, outF2, coSplit, coSplit2, nCo, co0 / 8, nhg);
}

static inline void conv_launch(const f16* in, const float* w, const float* b,
                               f16* out, int Cin, int co0, int nCo,
                               int Hin, int Win, int Hout, int Wout,
                               int stride, bool flip, hipStream_t s)
{
    const unsigned gx = (unsigned)((DD * (long long)Hout * Wout) / 2048);
    const float* wp = w + (size_t)co0 * Cin * 27;
    const float* bp = b + co0;
    const int cpc = (Cin / 2 < CP_CHUNK) ? Cin / 2 : CP_CHUNK;
    if (flip) {
        if (nCo % 4 == 0) {
            dim3 grid(gx, nCo / 4);
            conv3d_il_k<1, true, 4, true><<<grid, 256, (size_t)cpc * 27 * 4 * 4, s>>>(
                in, wp, bp, out, Cin, Hin, Win, Hout, Wout);
        } else {  // rec layer: nCo == 3, plain output
            dim3 grid(gx, 1);
            conv3d_il_k<1, true, 3, false><<<grid, 256, (size_t)cpc * 27 * 3 * 4, s>>>(
                in, wp, bp, out, Cin, Hin, Win, Hout, Wout);
        }
    } else {
        dim3 grid(gx, nCo / 8);
        conv3d_il_k<1, false, 8, true><<<grid, 256, (size_t)cpc * 27 * 8 * 4, s>>>(
            in, wp, bp, out, Cin, Hin, Win, Hout, Wout);
    }
}

static inline void conv_up_launch(const f16* ia, const f16* ib, const float* w,
                                  const float* b, f16* out, int Cin, int co0,
                                  int nCo, int Hlo, int Wlo, hipStream_t s)
{
    const unsigned gx = (unsigned)((DD * 4LL * Hlo * Wlo) / 2048);
    const int cpc = (Cin / 2 < CP_CHUNK) ? Cin / 2 : CP_CHUNK;
    if (nCo % 8 == 0) {
        dim3 grid(gx, nCo / 8);
        conv3d_up_il_k<8><<<grid, 256, (size_t)cpc * 27 * 8 * 4, s>>>(
            ia, ib, w + (size_t)co0 * Cin * 27, b + co0, out, Cin, Hlo, Wlo);
    } else {
        dim3 grid(gx, nCo / 4);
        conv3d_up_il_k<4><<<grid, 256, (size_t)cpc * 27 * 4 * 4, s>>>(
            ia, ib, w + (size_t)co0 * Cin * 27, b + co0, out, Cin, Hlo, Wlo);
    }
}

template<bool IL, typename TA1, typename TA2, typename TO>
static inline void pool_launch(const f16* z, const f16* f, TO* o, const TA1* a1,
                               const TA2* a2, int C, int HW, int rev,
                               hipStream_t s)
{
    const long long tot = (long long)C * HW;
    fo_pool_k<IL, TA1, TA2, TO><<<(unsigned)((tot + 255) / 256), 256, 0, s>>>(
        z, f, o, a1, a2, C, HW, rev);
}

static inline void pack_launch(const float* w, f16* outp, int CIN, int nCo,
                               int flip, hipStream_t s)
{
    const int total = (CIN / 8) * ((nCo + 7) / 8) * 9 * 64;
    pack_w_k<<<(total + 255) / 256, 256, 0, s>>>(w, outp, CIN, nCo, flip);
}

static inline void add_launch(f16* a, const f16* b, long long n, hipStream_t s)
{
    const long long n8 = n / 8;
    add_k<<<(unsigned)((n8 + 255) / 256), 256, 0, s>>>(a, b, n8);
}

// pack sizes in f16 elems (ceil co groups)
static constexpr size_t pk_sz(int CIN, int nCo)
{ return (size_t)(CIN / 8) * ((nCo + 7) / 8) * 9 * 64 * 8; }

// ---------------------------------------------------------------------------
// Memory plan (units of U). Pool = 56 U f16; packed weights (<1U) at 56U.
// r15 (halo-pass halving): NT=4 for e1..d2 (y-blocks halve -> halo staging
// halves); e0 single call (z->P, f->E0 in-place pool); d3 single call via
// TRI-output (z->D3 [32,48), f1->dead-E1 [0,8U), f2->G [48,56)). ws<300MB
// measured (saveFE never triggered) -> big-workspace tiers removed.
// All write extents audited against slots (r10 lesson).
// ---------------------------------------------------------------------------
static void run_net(const float* x, const float* const* W, const float* const* B,
                    float* out, f16* P, bool packed, hipStream_t s)
{
    const f16* np = nullptr;
    const float* npf = nullptr;
    f16* NPF16 = nullptr;

    // ---- packed-weight buffers at P + 56U ----------------------------------
    f16* WP = P + 56 * U;
    f16* PK_e0 = WP;                                  // 16,32
    f16* PK_e1 = PK_e0 + pk_sz(16, 32);               // 16,64
    f16* PK_e2 = PK_e1 + pk_sz(16, 64);               // 32,64
    f16* PK_e3 = PK_e2 + pk_sz(32, 64);               // 32,128
    f16* PK_e4 = PK_e3 + pk_sz(32, 128);              // 64,128
    f16* PK_d0 = PK_e4 + pk_sz(64, 128);              // 64,128 flip
    f16* PK_d2 = PK_d0 + pk_sz(64, 128);              // 32,64 flip
    // late packs reuse PK_d0's region (dead after d0 conv):
    f16* PK_d1 = PK_d0;                               // 64,64
    f16* PK_d3 = PK_d1 + pk_sz(64, 64);               // 32,32
    f16* PK_d4 = PK_d3 + pk_sz(32, 32);               // 16,32 flip
    f16* PK_rec = PK_d4 + pk_sz(16, 32);              // 16,3  flip
    if (packed) {
        pack_launch(W[1], PK_e0, 16, 32, 0, s);
        pack_launch(W[2], PK_e1, 16, 64, 0, s);
        pack_launch(W[3], PK_e2, 32, 64, 0, s);
        pack_launch(W[4], PK_e3, 32, 128, 0, s);
        pack_launch(W[5], PK_e4, 64, 128, 0, s);
        pack_launch(W[6], PK_d0, 64, 128, 1, s);
        pack_launch(W[8], PK_d2, 32, 64, 1, s);
    }

#define MFMA_CALL(S, F, CI, H, Wd, NTv, in_, wt_, wb_, bi_, out_, co0_, nco_, nhg_) \
    do { if (packed) mfma_launch<S, F, CI, H, Wd, NTv, true, true>(in_, wt_, (const f16x8*)(wb_), bi_, out_, NPF16, NPF16, COSPLIT_NONE, COSPLIT_NONE, co0_, nco_, nhg_, s); \
         else        mfma_launch<S, F, CI, H, Wd, NTv, false, true>(in_, wt_, nullptr, bi_, out_, NPF16, NPF16, COSPLIT_NONE, COSPLIT_NONE, co0_, nco_, nhg_, s); } while (0)

    fill_k<<<2048, 256, 0, s>>>(P, POOL_UNITS * U);

    f16* FE = P + 32 * U;
    // ---- fe = biqrnn(conv(x)) : 1 -> 48 gates -> 16 ch @256, chunks of 4 ---
    for (int a = 0; a < 16; a += 4) {
        conv_fe_k<<<992, 256, 0, s>>>(x, W[0] + (size_t)a * 27,        B[0] + a,      P);
        conv_fe_k<<<992, 256, 0, s>>>(x, W[0] + (size_t)(16 + a) * 27, B[0] + 16 + a, P + 4 * U);
        conv_fe_k<<<992, 256, 0, s>>>(x, W[0] + (size_t)(32 + a) * 27, B[0] + 32 + a, P + 8 * U);
        pool_launch<true, f16, float, f16>(P, P + 4 * U, P + 12 * U, np, npf, 4, 65536, 0, s);
        pool_launch<true, f16, float, f16>(P, P + 8 * U, FE + (size_t)a * U, P + 12 * U, npf, 4, 65536, 1, s);
    }

    // ---- e0 = qrnn(conv(fe), fwd) : 16 -> 32 -> 16 @256 (MFMA) -------------
    // r15: ONE call: z co0-15 -> P[0,16U), f co16-31 -> E0 [16U,32U) direct;
    // pool C=16 in-place over f (out == f == E0).
    f16* E0 = P + 16 * U;
    if (packed) {
        mfma_launch<1, false, 16, 256, 256, 2, true, true>(
            FE, W[1], (const f16x8*)PK_e0, B[1], P, E0, NPF16,
            16, COSPLIT_NONE, 0, 32, 4, s);
        pool_launch<true, f16, float, f16>(P, E0, E0, np, npf, 16, 65536, 0, s);
    } else {
        MFMA_CALL(1, false, 16, 256, 256, 1, FE, W[1], PK_e0, B[1], P, 0, 16, 4);
        for (int a = 0; a < 16; a += 8) {
            f16* G = P + 48 * U;
            MFMA_CALL(1, false, 16, 256, 256, 1, FE, W[1], PK_e0, B[1], G, 16 + a, 8, 4);
            pool_launch<true, f16, float, f16>(P + (size_t)a * U, G, E0 + (size_t)a * U,
                                               np, npf, 8, 65536, 0, s);
        }
    }
    // FE dead (recomputed later).

    // ---- e1 = qrnn(conv(e0, s2), rev) : 16 -> 64 -> 32 @128 (MFMA NT4) -----
    f16* E1 = P;
    {
        f16* G = P + 32 * U;
        MFMA_CALL(2, false, 16, 128, 128, 4, E0, W[2], PK_e1, B[2], G, 0, 64, 8);
        pool_launch<true, f16, float, f16>(G, G + 8 * U, E1, np, npf, 32, 16384, 1, s);
    }

    // ---- e2 = qrnn(conv(e1), fwd) : 32 -> 64 -> 32 @128 (MFMA NT4) ---------
    f16* E2 = P + 8 * U;
    {
        f16* G = P + 32 * U;
        MFMA_CALL(1, false, 32, 128, 128, 4, E1, W[3], PK_e2, B[3], G, 0, 64, 8);
        pool_launch<true, f16, float, f16>(G, G + 8 * U, E2, np, npf, 32, 16384, 0, s);
    }

    // ---- e3 = qrnn(conv(e2, s2), rev) : 32 -> 128 -> 64 @64 (MFMA NT4) -----
    f16* E3 = P + 32 * U;
    {
        f16* G = P + 48 * U;
        MFMA_CALL(2, false, 32, 64, 64, 4, E2, W[4], PK_e3, B[4], G, 0, 128, 16);
        pool_launch<true, f16, float, f16>(G, G + 4 * U, E3, np, npf, 64, 4096, 1, s);
    }

    // ---- e4 = qrnn(conv(e3), fwd) : 64 -> 128 -> 64 @64 (MFMA NT4) ---------
    f16* E4 = P + 40 * U;
    {
        f16* G = P + 48 * U;
        MFMA_CALL(1, false, 64, 64, 64, 4, E3, W[5], PK_e4, B[5], G, 0, 128, 16);
        pool_launch<true, f16, float, f16>(G, G + 4 * U, E4, np, npf, 64, 4096, 0, s);
    }

    // ---- d0 = qrnn(deconv(e4), rev) : 64 -> 128 -> 64 @64 (MFMA NT4 flip) --
    f16* D0 = P + 44 * U;
    {
        f16* G = P + 48 * U;
        MFMA_CALL(1, true, 64, 64, 64, 4, E4, W[6], PK_d0, B[6], G, 0, 128, 16);
        pool_launch<true, f16, float, f16>(G, G + 4 * U, D0, np, npf, 64, 4096, 1, s);
    }
    // E4 dead. PK_d0 dead -> repack region for d1/d3/d4/rec (stream-ordered).
    if (packed) {
        pack_launch(W[7],  PK_d1, 64, 64, 0, s);
        pack_launch(W[9],  PK_d3, 32, 32, 0, s);
        pack_launch(W[10], PK_d4, 16, 32, 1, s);
        pack_launch(W[11], PK_rec, 16, 3, 1, s);
    }

    // ---- d1 = qrnn(conv(up(d0+e3)), fwd) + e2 : 64 -> 64 -> 32 @128 --------
    // r15: ONE NT=4 call: z co0-31 -> D1 [36,44) (8U), f co32-63 -> G (8U).
    f16* D1 = P + 36 * U;
    if (packed) {
        f16* G = P + 48 * U;
        add_launch(D0, E3, 4 * U, s);
        mfma_up_launch<64, 64, 64, 4>(D0, (const f16x8*)PK_d1, B[7], D1,
                                      G, NPF16, 32, COSPLIT_NONE, 0, 64, 8, s);
        pool_launch<true, f16, float, f16>(D1, G, D1, E2, npf, 32, 16384, 0, s);
    } else {
        for (int a = 0; a < 32; a += 16) {
            f16* G = P + 48 * U;
            conv_up_launch(D0, E3, W[7], B[7], G,         64, a,      16, 64, 64, s);
            conv_up_launch(D0, E3, W[7], B[7], G + 4 * U, 64, 32 + a, 16, 64, 64, s);
            pool_launch<true, f16, float, f16>(G, G + 4 * U, D1 + (size_t)a * V2,
                                               E2 + (size_t)a * V2, npf, 16, 16384, 0, s);
        }
    }
    // E2, E3, D0 dead.

    // ---- d2 = qrnn(deconv(d1), rev) : 32 -> 64 -> 32 @128 (MFMA NT4 flip) --
    // r15: ONE call: z co0-31 -> D2 [8,16) (8U over dead E2), f co32-63 -> G.
    f16* D2 = P + 8 * U;
    if (packed) {
        f16* G = P + 48 * U;
        if (true) {
            if (packed) mfma_launch<1, true, 32, 128, 128, 4, true, true>(
                D1, W[8], (const f16x8*)PK_d2, B[8], D2, G, NPF16,
                32, COSPLIT_NONE, 0, 64, 8, s);
        }
        pool_launch<true, f16, float, f16>(D2, G, D2, np, npf, 32, 16384, 1, s);
    } else {
        for (int a = 0; a < 32; a += 16) {
            f16* G = P + 48 * U;
            MFMA_CALL(1, true, 32, 128, 128, 1, D1, W[8], PK_d2, B[8], G,         a,      16, 8);
            MFMA_CALL(1, true, 32, 128, 128, 1, D1, W[8], PK_d2, B[8], G + 4 * U, 32 + a, 16, 8);
            pool_launch<true, f16, float, f16>(G, G + 4 * U, D2 + (size_t)a * V2, np, npf, 16, 16384, 1, s);
        }
    }
    // D1 dead.

    // ---- d3 = qrnn(conv(up(d2+e1)), fwd) + e0 : 32 -> 32 -> 16 @256 --------
    // r15: ONE call, TRI-output: z co0-15 -> D3 [32,48), f co16-23 -> dead-E1
    // [0,8U), f co24-31 -> G [48,56). Two 8-ch pools, in-place over z.
    f16* D3 = P + 32 * U;  // fresh 16U
    if (packed) {
        f16* G = P + 48 * U;
        add_launch(D2, E1, 8 * U, s);   // E1 region [0,8U) dead after this
        mfma_up_launch<32, 128, 128, 2>(D2, (const f16x8*)PK_d3, B[9], D3,
                                        P, G, 16, 24, 0, 32, 4, s);
        pool_launch<true, f16, float, f16>(D3, P, D3, E0, npf, 8, 65536, 0, s);
        pool_launch<true, f16, float, f16>(D3 + 8 * U, G, D3 + 8 * U,
                                           E0 + 8 * U, npf, 8, 65536, 0, s);
    } else {
        for (int a = 0; a < 16; a += 4) {
            f16* G = P + 48 * U;
            conv_up_launch(D2, E1, W[9], B[9], G,         32, a,      4, 128, 128, s);
            conv_up_launch(D2, E1, W[9], B[9], G + 4 * U, 32, 16 + a, 4, 128, 128, s);
            pool_launch<true, f16, float, f16>(G, G + 4 * U, D3 + (size_t)a * U,
                                               E0 + (size_t)a * U, npf, 4, 65536, 0, s);
        }
    }
    // E0, E1, D2 dead.

    // ---- recompute fe -> FE2 = [0,16), gates at [16,32) --------------------
    f16* FE2 = P;
    for (int a = 0; a < 16; a += 4) {
        f16* G = P + 16 * U;
        conv_fe_k<<<992, 256, 0, s>>>(x, W[0] + (size_t)a * 27,        B[0] + a,      G);
        conv_fe_k<<<992, 256, 0, s>>>(x, W[0] + (size_t)(16 + a) * 27, B[0] + 16 + a, G + 4 * U);
        conv_fe_k<<<992, 256, 0, s>>>(x, W[0] + (size_t)(32 + a) * 27, B[0] + 32 + a, G + 8 * U);
        pool_launch<true, f16, float, f16>(G, G + 4 * U, G + 12 * U, np, npf, 4, 65536, 0, s);
        pool_launch<true, f16, float, f16>(G, G + 8 * U, FE2 + (size_t)a * U, G + 12 * U, npf, 4, 65536, 1, s);
    }

    // ---- d4 = qrnn(deconv(d3), rev) + fe : 16 -> 32 -> 16 @256 (dual) ------
    f16* D4 = P + 16 * U;
    if (packed) {
        f16* G = P + 48 * U;
        mfma_launch<1, true, 16, 256, 256, 2, true, true>(
            D3, W[10], (const f16x8*)PK_d4, B[10], D4, G, NPF16,
            16, COSPLIT_NONE, 0, 24, 4, s);
        pool_launch<true, f16, float, f16>(D4, G, D4, FE2, npf, 8, 65536, 1, s);
        mfma_launch<1, true, 16, 256, 256, 1, true, true>(
            D3, W[10], (const f16x8*)PK_d4, B[10], G, NPF16, NPF16,
            COSPLIT_NONE, COSPLIT_NONE, 24, 8, 4, s);
        pool_launch<true, f16, float, f16>(D4 + 8 * U, G, D4 + 8 * U,
                                           FE2 + 8 * U, npf, 8, 65536, 1, s);
    } else {
        for (int a = 0; a < 16; a += 4) {
            f16* G = P + 48 * U;
            conv_launch(D3, W[10], B[10], G,         16, a,      4, 256, 256, 256, 256, 1, true, s);
            conv_launch(D3, W[10], B[10], G + 4 * U, 16, 16 + a, 4, 256, 256, 256, 256, 1, true, s);
            pool_launch<true, f16, float, f16>(G, G + 4 * U, D4 + (size_t)a * U,
                                               FE2 + (size_t)a * U, npf, 4, 65536, 1, s);
        }
    }
    // D3, FE2 dead.

    // ---- out = biqrnn(deconv(d4)) + x : 16 -> 3 -> 1 @256 -> fp32 d_out ----
    {
        f16* G = P + 32 * U;   // plain: ch0 z, ch1 f1, ch2 f2 (3U, D3 dead)
        f16* TMP = P + 35 * U;
        if (packed) {
            mfma_launch<1, true, 16, 256, 256, 1, true, false>(
                D4, W[11], (const f16x8*)PK_rec, B[11], G, NPF16, NPF16,
                COSPLIT_NONE, COSPLIT_NONE, 0, 3, 1, s);
        } else {
            conv_launch(D4, W[11], B[11], G, 16, 0, 3, 256, 256, 256, 256, 1, true, s);
        }
        pool_launch<false, f16, float, f16>(G, G + 1 * U, TMP, np, npf, 1, 65536, 0, s);
        pool_launch<false, f16, float, float>(G, G + 2 * U, out, TMP, x, 1, 65536, 1, s);
    }
#undef MFMA_CALL
}

extern "C" void kernel_launch(void* const* d_in, const int* in_sizes, int n_in,
                              void* d_out, int out_size, void* d_ws, size_t ws_size,
                              hipStream_t stream)
{
    const float* x = (const float*)d_in[0];
    const float* W[12];
    const float* B[12];
    for (int i = 0; i < 12; ++i) {
        W[i] = (const float*)d_in[1 + 2 * i];
        B[i] = (const float*)d_in[2 + 2 * i];
    }

    const size_t need_base = (size_t)(POOL_UNITS * U) * sizeof(f16);     // ~227 MB
    const size_t need_pack = (size_t)(57 * U) * sizeof(f16);             // +~4 MB
    if (ws_size >= need_pack) {
        run_net(x, W, B, (float*)d_out, (f16*)d_ws, true, stream);
    } else if (ws_size >= need_base) {
        run_net(x, W, B, (float*)d_out, (f16*)d_ws, false, stream);
    } else {
        const float ws_mb = (float)((double)ws_size / 1048576.0);
        diag_k<<<(out_size + 255) / 256, 256, 0, stream>>>(
            (float*)d_out, ws_mb, out_size);
    }
}